// Round 1
// baseline (1462.378 us; speedup 1.0000x reference)
//
#include <hip/hip_runtime.h>
#include <hip/hip_bf16.h>

#define N_NODES 100000
#define N_EDGES 1600000
#define DF 64

// ---------------- degree histogram ----------------
__global__ void hist_kernel(const int* __restrict__ row, const int* __restrict__ col,
                            int* __restrict__ deg_out, int* __restrict__ deg_in, int E) {
    int e = blockIdx.x * blockDim.x + threadIdx.x;
    if (e < E) {
        atomicAdd(&deg_out[row[e]], 1);
        atomicAdd(&deg_in[col[e]], 1);
    }
}

// ---------------- deg^-0.25 ----------------
__global__ void dpow_kernel(const int* __restrict__ deg_out, const int* __restrict__ deg_in,
                            float* __restrict__ dp_out, float* __restrict__ dp_in, int n) {
    int i = blockIdx.x * blockDim.x + threadIdx.x;
    if (i < n) {
        int a = deg_out[i];
        int b = deg_in[i];
        dp_out[i] = (a > 0) ? rsqrtf(sqrtf((float)a)) : 0.f;
        dp_in[i]  = (b > 0) ? rsqrtf(sqrtf((float)b)) : 0.f;
    }
}

// ---------------- scan: per-block partial sums ----------------
__global__ void scan_partial_kernel(const int* __restrict__ deg, int n, int* __restrict__ partial) {
    __shared__ int sdata[256];
    int idx = blockIdx.x * 256 + threadIdx.x;
    int v = (idx < n) ? deg[idx] : 0;
    sdata[threadIdx.x] = v;
    __syncthreads();
    for (int s = 128; s > 0; s >>= 1) {
        if (threadIdx.x < s) sdata[threadIdx.x] += sdata[threadIdx.x + s];
        __syncthreads();
    }
    if (threadIdx.x == 0) partial[blockIdx.x] = sdata[0];
}

// ---------------- scan: exclusive scan of partials (single block, nblk <= 512) ----------------
__global__ void scan_mid_kernel(int* __restrict__ partial, int nblk) {
    __shared__ int s[512];
    int t = threadIdx.x;
    int v = (t < nblk) ? partial[t] : 0;
    s[t] = v;
    __syncthreads();
    for (int off = 1; off < 512; off <<= 1) {
        int add = (t >= off) ? s[t - off] : 0;
        __syncthreads();
        s[t] += add;
        __syncthreads();
    }
    if (t < nblk) partial[t] = s[t] - v;   // exclusive
}

// ---------------- scan: emit final ptr array ----------------
__global__ void scan_emit_kernel(const int* __restrict__ deg, const int* __restrict__ partial,
                                 int n, int* __restrict__ ptr) {
    __shared__ int buf[256];
    int t = threadIdx.x;
    int idx = blockIdx.x * 256 + t;
    int v = (idx < n) ? deg[idx] : 0;
    buf[t] = v;
    __syncthreads();
    for (int off = 1; off < 256; off <<= 1) {
        int add = (t >= off) ? buf[t - off] : 0;
        __syncthreads();
        buf[t] += add;
        __syncthreads();
    }
    int excl = buf[t] - v + partial[blockIdx.x];
    if (idx < n) ptr[idx] = excl;
    if (idx == n - 1) ptr[n] = excl + v;
}

// ---------------- CSR fill (both directions) ----------------
__global__ void fill_kernel(const int* __restrict__ row, const int* __restrict__ col,
                            const int* __restrict__ row_ptr, const int* __restrict__ col_ptr,
                            int* __restrict__ row_cur, int* __restrict__ col_cur,
                            int* __restrict__ csr_row_col, int* __restrict__ csr_col_row, int E) {
    int e = blockIdx.x * blockDim.x + threadIdx.x;
    if (e < E) {
        int r = row[e], c = col[e];
        int p = row_ptr[r] + atomicAdd(&row_cur[r], 1);
        csr_row_col[p] = c;
        int q = col_ptr[c] + atomicAdd(&col_cur[c], 1);
        csr_col_row[q] = r;
    }
}

// ---------------- pull SpMM: dst[r][lane] = dp_dst[r] * sum_e dp_src[nbr] * src[nbr][lane] ----------------
__global__ __launch_bounds__(256) void spmm_pull_kernel(
        const int* __restrict__ ptr, const int* __restrict__ nbr,
        const float* __restrict__ dp_dst, const float* __restrict__ dp_src,
        const float* __restrict__ src, float* __restrict__ dst, int n) {
    int wid = (blockIdx.x * blockDim.x + threadIdx.x) >> 6;   // wave = node
    int lane = threadIdx.x & 63;
    if (wid >= n) return;
    int beg = ptr[wid], end = ptr[wid + 1];
    float acc = 0.f;
    for (int p = beg; p < end; ++p) {
        int c = nbr[p];
        float w = dp_src[c];
        acc += w * src[(size_t)c * DF + lane];
    }
    dst[(size_t)wid * DF + lane] = acc * dp_dst[wid];
}

// ---------------- bias total ----------------
__global__ void bias_total_kernel(const float* __restrict__ b_sd, const float* __restrict__ b_ds,
                                  float* __restrict__ bias_tot) {
    int o = threadIdx.x;   // 64 threads
    float s = 0.f, sc = 1.f;
    for (int i = 0; i < 3; ++i) {
        s += sc * (0.5f * b_sd[i * 64 + o] + 0.5f * b_ds[i * 64 + o]);
        sc *= 0.5f;
    }
    bias_tot[o] = s;
}

// ---------------- out init with bias ----------------
__global__ void init_out_kernel(float* __restrict__ out, const float* __restrict__ bias_tot, int total) {
    int i = blockIdx.x * blockDim.x + threadIdx.x;
    if (i < total) out[i] = bias_tot[i & 63];
}

// ---------------- GEMM accumulate: out[n][o] += coef * sum_d Y[n][d] * W[o][d] ----------------
__global__ __launch_bounds__(256) void gemm_acc_kernel(
        const float* __restrict__ Y, const float* __restrict__ W,
        float coef, float* __restrict__ out, int n) {
    __shared__ float Ws[64 * 65];
    __shared__ float Ys[64 * 65];
    int t = threadIdx.x;
    for (int i = t; i < 4096; i += 256) {
        int o = i >> 6, d = i & 63;
        Ws[o * 65 + d] = W[i];
    }
    int node0 = blockIdx.x * 64;
    for (int i = t; i < 4096; i += 256) {
        int r = i >> 6, d = i & 63;
        int nd = node0 + r;
        Ys[r * 65 + d] = (nd < n) ? Y[(size_t)nd * DF + d] : 0.f;
    }
    __syncthreads();
    int tx = t & 15, ty = t >> 4;
    float acc[4][4] = {};
    const float* yp = &Ys[(ty * 4) * 65];
    const float* wp = &Ws[(tx * 4) * 65];
    for (int k = 0; k < 64; ++k) {
        float yv[4], wv[4];
#pragma unroll
        for (int i = 0; i < 4; ++i) yv[i] = yp[i * 65 + k];
#pragma unroll
        for (int j = 0; j < 4; ++j) wv[j] = wp[j * 65 + k];
#pragma unroll
        for (int i = 0; i < 4; ++i)
#pragma unroll
            for (int j = 0; j < 4; ++j) acc[i][j] += yv[i] * wv[j];
    }
#pragma unroll
    for (int i = 0; i < 4; ++i) {
        int nd = node0 + ty * 4 + i;
        if (nd < n) {
            float4* outp = (float4*)&out[(size_t)nd * DF + tx * 4];
            float4 v = *outp;
            v.x += coef * acc[i][0];
            v.y += coef * acc[i][1];
            v.z += coef * acc[i][2];
            v.w += coef * acc[i][3];
            *outp = v;
        }
    }
}

extern "C" void kernel_launch(void* const* d_in, const int* in_sizes, int n_in,
                              void* d_out, int out_size, void* d_ws, size_t ws_size,
                              hipStream_t stream) {
    const int N = N_NODES, E = N_EDGES;
    const float* x    = (const float*)d_in[0];
    const int*   ei   = (const int*)d_in[1];
    const int*   row  = ei;
    const int*   col  = ei + E;
    const float* W_sd = (const float*)d_in[2];
    const float* b_sd = (const float*)d_in[3];
    const float* W_ds = (const float*)d_in[4];
    const float* b_ds = (const float*)d_in[5];
    float* out = (float*)d_out;

    char* ws = (char*)d_ws;
    size_t off = 0;
    auto alloc = [&](size_t bytes) -> void* {
        void* p = ws + off;
        off += (bytes + 255) & ~(size_t)255;
        return p;
    };
    int*   deg_out = (int*)alloc((size_t)N * 4);
    int*   deg_in  = (int*)alloc((size_t)N * 4);
    int*   row_ptr = (int*)alloc((size_t)(N + 1) * 4);
    int*   col_ptr = (int*)alloc((size_t)(N + 1) * 4);
    int*   row_cur = (int*)alloc((size_t)N * 4);
    int*   col_cur = (int*)alloc((size_t)N * 4);
    int*   part_a  = (int*)alloc(512 * 4);
    int*   part_b  = (int*)alloc(512 * 4);
    float* dp_out  = (float*)alloc((size_t)N * 4);
    float* dp_in   = (float*)alloc((size_t)N * 4);
    int*   csr_row_col = (int*)alloc((size_t)E * 4);
    int*   csr_col_row = (int*)alloc((size_t)E * 4);
    float* bias_tot = (float*)alloc(64 * 4);
    float* yA = (float*)alloc((size_t)N * DF * 4);
    float* yB = (float*)alloc((size_t)N * DF * 4);
    float* yT = (float*)alloc((size_t)N * DF * 4);

    // zero the counters
    hipMemsetAsync(deg_out, 0, (size_t)N * 4, stream);
    hipMemsetAsync(deg_in,  0, (size_t)N * 4, stream);
    hipMemsetAsync(row_cur, 0, (size_t)N * 4, stream);
    hipMemsetAsync(col_cur, 0, (size_t)N * 4, stream);

    const int eblk = (E + 255) / 256;          // 6250
    const int nblk = (N + 255) / 256;          // 391
    hist_kernel<<<eblk, 256, 0, stream>>>(row, col, deg_out, deg_in, E);
    dpow_kernel<<<nblk, 256, 0, stream>>>(deg_out, deg_in, dp_out, dp_in, N);

    // CSR by row
    scan_partial_kernel<<<nblk, 256, 0, stream>>>(deg_out, N, part_a);
    scan_mid_kernel<<<1, 512, 0, stream>>>(part_a, nblk);
    scan_emit_kernel<<<nblk, 256, 0, stream>>>(deg_out, part_a, N, row_ptr);
    // CSR by col
    scan_partial_kernel<<<nblk, 256, 0, stream>>>(deg_in, N, part_b);
    scan_mid_kernel<<<1, 512, 0, stream>>>(part_b, nblk);
    scan_emit_kernel<<<nblk, 256, 0, stream>>>(deg_in, part_b, N, col_ptr);

    fill_kernel<<<eblk, 256, 0, stream>>>(row, col, row_ptr, col_ptr,
                                          row_cur, col_cur, csr_row_col, csr_col_row, E);

    // out = total bias
    bias_total_kernel<<<1, 64, 0, stream>>>(b_sd, b_ds, bias_tot);
    const int total = N * DF;
    init_out_kernel<<<(total + 255) / 256, 256, 0, stream>>>(out, bias_tot, total);

    const int spmm_blk = (N * 64 + 255) / 256;   // one wave per node
    const int gblk = (N + 63) / 64;              // 1563

    // i = 0:  yA = A x ; yT = A^T x
    spmm_pull_kernel<<<spmm_blk, 256, 0, stream>>>(row_ptr, csr_row_col, dp_out, dp_in, x, yA, N);
    spmm_pull_kernel<<<spmm_blk, 256, 0, stream>>>(col_ptr, csr_col_row, dp_in, dp_out, x, yT, N);
    gemm_acc_kernel<<<gblk, 256, 0, stream>>>(yA, W_sd + 0 * 4096, 0.5f * 1.0f, out, N);
    gemm_acc_kernel<<<gblk, 256, 0, stream>>>(yT, W_ds + 0 * 4096, 0.5f * 1.0f, out, N);

    // i = 1:  yB = A yA ; yT = A^T yB   (reference propagates the NEW y)
    spmm_pull_kernel<<<spmm_blk, 256, 0, stream>>>(row_ptr, csr_row_col, dp_out, dp_in, yA, yB, N);
    spmm_pull_kernel<<<spmm_blk, 256, 0, stream>>>(col_ptr, csr_col_row, dp_in, dp_out, yB, yT, N);
    gemm_acc_kernel<<<gblk, 256, 0, stream>>>(yB, W_sd + 1 * 4096, 0.5f * 0.5f, out, N);
    gemm_acc_kernel<<<gblk, 256, 0, stream>>>(yT, W_ds + 1 * 4096, 0.5f * 0.5f, out, N);

    // i = 2:  yA = A yB ; yT = A^T yA
    spmm_pull_kernel<<<spmm_blk, 256, 0, stream>>>(row_ptr, csr_row_col, dp_out, dp_in, yB, yA, N);
    spmm_pull_kernel<<<spmm_blk, 256, 0, stream>>>(col_ptr, csr_col_row, dp_in, dp_out, yA, yT, N);
    gemm_acc_kernel<<<gblk, 256, 0, stream>>>(yA, W_sd + 2 * 4096, 0.5f * 0.25f, out, N);
    gemm_acc_kernel<<<gblk, 256, 0, stream>>>(yT, W_ds + 2 * 4096, 0.5f * 0.25f, out, N);
}

// Round 2
// 925.777 us; speedup vs baseline: 1.5796x; 1.5796x over previous
//
#include <hip/hip_runtime.h>
#include <hip/hip_bf16.h>

#define N_NODES 100000
#define N_EDGES 1600000
#define DF 64

// ---------------- degree histogram ----------------
__global__ void hist_kernel(const int* __restrict__ row, const int* __restrict__ col,
                            int* __restrict__ deg_out, int* __restrict__ deg_in, int E) {
    int e = blockIdx.x * blockDim.x + threadIdx.x;
    if (e < E) {
        atomicAdd(&deg_out[row[e]], 1);
        atomicAdd(&deg_in[col[e]], 1);
    }
}

// ---------------- deg^-0.25 ----------------
__global__ void dpow_kernel(const int* __restrict__ deg_out, const int* __restrict__ deg_in,
                            float* __restrict__ dp_out, float* __restrict__ dp_in, int n) {
    int i = blockIdx.x * blockDim.x + threadIdx.x;
    if (i < n) {
        int a = deg_out[i];
        int b = deg_in[i];
        dp_out[i] = (a > 0) ? rsqrtf(sqrtf((float)a)) : 0.f;
        dp_in[i]  = (b > 0) ? rsqrtf(sqrtf((float)b)) : 0.f;
    }
}

// ---------------- scan: per-block partial sums ----------------
__global__ void scan_partial_kernel(const int* __restrict__ deg, int n, int* __restrict__ partial) {
    __shared__ int sdata[256];
    int idx = blockIdx.x * 256 + threadIdx.x;
    int v = (idx < n) ? deg[idx] : 0;
    sdata[threadIdx.x] = v;
    __syncthreads();
    for (int s = 128; s > 0; s >>= 1) {
        if (threadIdx.x < s) sdata[threadIdx.x] += sdata[threadIdx.x + s];
        __syncthreads();
    }
    if (threadIdx.x == 0) partial[blockIdx.x] = sdata[0];
}

// ---------------- scan: exclusive scan of partials (single block, nblk <= 512) ----------------
__global__ void scan_mid_kernel(int* __restrict__ partial, int nblk) {
    __shared__ int s[512];
    int t = threadIdx.x;
    int v = (t < nblk) ? partial[t] : 0;
    s[t] = v;
    __syncthreads();
    for (int off = 1; off < 512; off <<= 1) {
        int add = (t >= off) ? s[t - off] : 0;
        __syncthreads();
        s[t] += add;
        __syncthreads();
    }
    if (t < nblk) partial[t] = s[t] - v;   // exclusive
}

// ---------------- scan: emit final ptr array ----------------
__global__ void scan_emit_kernel(const int* __restrict__ deg, const int* __restrict__ partial,
                                 int n, int* __restrict__ ptr) {
    __shared__ int buf[256];
    int t = threadIdx.x;
    int idx = blockIdx.x * 256 + t;
    int v = (idx < n) ? deg[idx] : 0;
    buf[t] = v;
    __syncthreads();
    for (int off = 1; off < 256; off <<= 1) {
        int add = (t >= off) ? buf[t - off] : 0;
        __syncthreads();
        buf[t] += add;
        __syncthreads();
    }
    int excl = buf[t] - v + partial[blockIdx.x];
    if (idx < n) ptr[idx] = excl;
    if (idx == n - 1) ptr[n] = excl + v;
}

// ---------------- CSR fill (both directions) ----------------
__global__ void fill_kernel(const int* __restrict__ row, const int* __restrict__ col,
                            const int* __restrict__ row_ptr, const int* __restrict__ col_ptr,
                            int* __restrict__ row_cur, int* __restrict__ col_cur,
                            int* __restrict__ csr_row_col, int* __restrict__ csr_col_row, int E) {
    int e = blockIdx.x * blockDim.x + threadIdx.x;
    if (e < E) {
        int r = row[e], c = col[e];
        int p = row_ptr[r] + atomicAdd(&row_cur[r], 1);
        csr_row_col[p] = c;
        int q = col_ptr[c] + atomicAdd(&col_cur[c], 1);
        csr_col_row[q] = r;
    }
}

// ---------------- pull SpMM v2: wave = node; 4 edge-slots x 16 float4-lanes ----------------
__global__ __launch_bounds__(256) void spmm_pull_kernel(
        const int* __restrict__ ptr, const int* __restrict__ nbr,
        const float* __restrict__ dp_dst, const float* __restrict__ dp_src,
        const float* __restrict__ src, float* __restrict__ dst, int n) {
    int wid = (blockIdx.x * blockDim.x + threadIdx.x) >> 6;   // wave = node
    int lane = threadIdx.x & 63;
    if (wid >= n) return;
    int slot = lane >> 4;     // edge slot 0..3
    int d4   = lane & 15;     // float4 index within the 64-float row
    int beg = ptr[wid], end = ptr[wid + 1];
    float4 acc = {0.f, 0.f, 0.f, 0.f};
    for (int p = beg + slot; p < end; p += 4) {
        int c = nbr[p];
        float w = dp_src[c];
        const float4 v = *(const float4*)&src[(size_t)c * DF + d4 * 4];
        acc.x += w * v.x;
        acc.y += w * v.y;
        acc.z += w * v.z;
        acc.w += w * v.w;
    }
    // reduce the 4 edge-slots (lanes xor 16, 32)
    acc.x += __shfl_xor(acc.x, 16);
    acc.y += __shfl_xor(acc.y, 16);
    acc.z += __shfl_xor(acc.z, 16);
    acc.w += __shfl_xor(acc.w, 16);
    acc.x += __shfl_xor(acc.x, 32);
    acc.y += __shfl_xor(acc.y, 32);
    acc.z += __shfl_xor(acc.z, 32);
    acc.w += __shfl_xor(acc.w, 32);
    if (slot == 0) {
        float s = dp_dst[wid];
        float4 o = { acc.x * s, acc.y * s, acc.z * s, acc.w * s };
        *(float4*)&dst[(size_t)wid * DF + d4 * 4] = o;
    }
}

// ---------------- bias total ----------------
__global__ void bias_total_kernel(const float* __restrict__ b_sd, const float* __restrict__ b_ds,
                                  float* __restrict__ bias_tot) {
    int o = threadIdx.x;   // 64 threads
    float s = 0.f, sc = 1.f;
    for (int i = 0; i < 3; ++i) {
        s += sc * (0.5f * b_sd[i * 64 + o] + 0.5f * b_ds[i * 64 + o]);
        sc *= 0.5f;
    }
    bias_tot[o] = s;
}

// ---------------- fused dual GEMM accumulate:
//   out[n][o] (+)= coef * ( sum_d YA[n][d]*Wa[o][d] + sum_d YB[n][d]*Wb[o][d] )  (+ bias on first)
__global__ __launch_bounds__(256) void gemm2_kernel(
        const float* __restrict__ YA, const float* __restrict__ YB,
        const float* __restrict__ Wa, const float* __restrict__ Wb,
        const float* __restrict__ bias_tot, float coef,
        float* __restrict__ out, int n, int add_bias) {
    __shared__ float Was[64 * 65];
    __shared__ float Wbs[64 * 65];
    __shared__ float Yas[64 * 65];
    __shared__ float Ybs[64 * 65];
    int t = threadIdx.x;
    int node0 = blockIdx.x * 64;
    // stage weights (row-major [o][d]) and Y tiles (row-major [node][d]) into LDS, pitch 65
    for (int i = t; i < 1024; i += 256) {            // 1024 float4 per 64x64 tile
        int r = i >> 4, c4 = (i & 15) * 4;
        float4 wa = ((const float4*)Wa)[i];
        float4 wb = ((const float4*)Wb)[i];
        Was[r * 65 + c4 + 0] = wa.x; Was[r * 65 + c4 + 1] = wa.y;
        Was[r * 65 + c4 + 2] = wa.z; Was[r * 65 + c4 + 3] = wa.w;
        Wbs[r * 65 + c4 + 0] = wb.x; Wbs[r * 65 + c4 + 1] = wb.y;
        Wbs[r * 65 + c4 + 2] = wb.z; Wbs[r * 65 + c4 + 3] = wb.w;
        int nd = node0 + r;
        float4 ya = {0,0,0,0}, yb = {0,0,0,0};
        if (nd < n) {
            ya = *(const float4*)&YA[(size_t)nd * DF + c4];
            yb = *(const float4*)&YB[(size_t)nd * DF + c4];
        }
        Yas[r * 65 + c4 + 0] = ya.x; Yas[r * 65 + c4 + 1] = ya.y;
        Yas[r * 65 + c4 + 2] = ya.z; Yas[r * 65 + c4 + 3] = ya.w;
        Ybs[r * 65 + c4 + 0] = yb.x; Ybs[r * 65 + c4 + 1] = yb.y;
        Ybs[r * 65 + c4 + 2] = yb.z; Ybs[r * 65 + c4 + 3] = yb.w;
    }
    __syncthreads();
    int tx = t & 15, ty = t >> 4;
    float acc[4][4] = {};
    const float* yap = &Yas[(ty * 4) * 65];
    const float* ybp = &Ybs[(ty * 4) * 65];
    const float* wap = &Was[(tx * 4) * 65];
    const float* wbp = &Wbs[(tx * 4) * 65];
    for (int k = 0; k < 64; ++k) {
        float ya[4], yb[4], wa[4], wb[4];
#pragma unroll
        for (int i = 0; i < 4; ++i) { ya[i] = yap[i * 65 + k]; yb[i] = ybp[i * 65 + k]; }
#pragma unroll
        for (int j = 0; j < 4; ++j) { wa[j] = wap[j * 65 + k]; wb[j] = wbp[j * 65 + k]; }
#pragma unroll
        for (int i = 0; i < 4; ++i)
#pragma unroll
            for (int j = 0; j < 4; ++j)
                acc[i][j] += ya[i] * wa[j] + yb[i] * wb[j];
    }
#pragma unroll
    for (int i = 0; i < 4; ++i) {
        int nd = node0 + ty * 4 + i;
        if (nd < n) {
            float4* outp = (float4*)&out[(size_t)nd * DF + tx * 4];
            float4 v;
            if (add_bias) v = *(const float4*)&bias_tot[tx * 4];
            else          v = *outp;
            v.x += coef * acc[i][0];
            v.y += coef * acc[i][1];
            v.z += coef * acc[i][2];
            v.w += coef * acc[i][3];
            *outp = v;
        }
    }
}

extern "C" void kernel_launch(void* const* d_in, const int* in_sizes, int n_in,
                              void* d_out, int out_size, void* d_ws, size_t ws_size,
                              hipStream_t stream) {
    const int N = N_NODES, E = N_EDGES;
    const float* x    = (const float*)d_in[0];
    const int*   ei   = (const int*)d_in[1];
    const int*   row  = ei;
    const int*   col  = ei + E;
    const float* W_sd = (const float*)d_in[2];
    const float* b_sd = (const float*)d_in[3];
    const float* W_ds = (const float*)d_in[4];
    const float* b_ds = (const float*)d_in[5];
    float* out = (float*)d_out;

    char* ws = (char*)d_ws;
    size_t off = 0;
    auto alloc = [&](size_t bytes) -> void* {
        void* p = ws + off;
        off += (bytes + 255) & ~(size_t)255;
        return p;
    };
    int*   deg_out = (int*)alloc((size_t)N * 4);
    int*   deg_in  = (int*)alloc((size_t)N * 4);
    int*   row_ptr = (int*)alloc((size_t)(N + 1) * 4);
    int*   col_ptr = (int*)alloc((size_t)(N + 1) * 4);
    int*   row_cur = (int*)alloc((size_t)N * 4);
    int*   col_cur = (int*)alloc((size_t)N * 4);
    int*   part_a  = (int*)alloc(512 * 4);
    int*   part_b  = (int*)alloc(512 * 4);
    float* dp_out  = (float*)alloc((size_t)N * 4);
    float* dp_in   = (float*)alloc((size_t)N * 4);
    int*   csr_row_col = (int*)alloc((size_t)E * 4);
    int*   csr_col_row = (int*)alloc((size_t)E * 4);
    float* bias_tot = (float*)alloc(64 * 4);
    float* yA = (float*)alloc((size_t)N * DF * 4);
    float* yB = (float*)alloc((size_t)N * DF * 4);
    float* yT = (float*)alloc((size_t)N * DF * 4);

    // zero the counters
    hipMemsetAsync(deg_out, 0, (size_t)N * 4, stream);
    hipMemsetAsync(deg_in,  0, (size_t)N * 4, stream);
    hipMemsetAsync(row_cur, 0, (size_t)N * 4, stream);
    hipMemsetAsync(col_cur, 0, (size_t)N * 4, stream);

    const int eblk = (E + 255) / 256;          // 6250
    const int nblk = (N + 255) / 256;          // 391
    hist_kernel<<<eblk, 256, 0, stream>>>(row, col, deg_out, deg_in, E);
    dpow_kernel<<<nblk, 256, 0, stream>>>(deg_out, deg_in, dp_out, dp_in, N);

    // CSR by row
    scan_partial_kernel<<<nblk, 256, 0, stream>>>(deg_out, N, part_a);
    scan_mid_kernel<<<1, 512, 0, stream>>>(part_a, nblk);
    scan_emit_kernel<<<nblk, 256, 0, stream>>>(deg_out, part_a, N, row_ptr);
    // CSR by col
    scan_partial_kernel<<<nblk, 256, 0, stream>>>(deg_in, N, part_b);
    scan_mid_kernel<<<1, 512, 0, stream>>>(part_b, nblk);
    scan_emit_kernel<<<nblk, 256, 0, stream>>>(deg_in, part_b, N, col_ptr);

    fill_kernel<<<eblk, 256, 0, stream>>>(row, col, row_ptr, col_ptr,
                                          row_cur, col_cur, csr_row_col, csr_col_row, E);

    bias_total_kernel<<<1, 64, 0, stream>>>(b_sd, b_ds, bias_tot);

    const int spmm_blk = (N * 64 + 255) / 256;   // one wave per node
    const int gblk = (N + 63) / 64;              // 1563

    // i = 0:  yA = A x ; yT = A^T x ; out = bias + 0.5*(yA Wsd0^T + yT Wds0^T)
    spmm_pull_kernel<<<spmm_blk, 256, 0, stream>>>(row_ptr, csr_row_col, dp_out, dp_in, x, yA, N);
    spmm_pull_kernel<<<spmm_blk, 256, 0, stream>>>(col_ptr, csr_col_row, dp_in, dp_out, x, yT, N);
    gemm2_kernel<<<gblk, 256, 0, stream>>>(yA, yT, W_sd + 0 * 4096, W_ds + 0 * 4096,
                                           bias_tot, 0.5f, out, N, 1);

    // i = 1:  yB = A yA ; yT = A^T yB  (reference propagates the NEW y)
    spmm_pull_kernel<<<spmm_blk, 256, 0, stream>>>(row_ptr, csr_row_col, dp_out, dp_in, yA, yB, N);
    spmm_pull_kernel<<<spmm_blk, 256, 0, stream>>>(col_ptr, csr_col_row, dp_in, dp_out, yB, yT, N);
    gemm2_kernel<<<gblk, 256, 0, stream>>>(yB, yT, W_sd + 1 * 4096, W_ds + 1 * 4096,
                                           bias_tot, 0.25f, out, N, 0);

    // i = 2:  yA = A yB ; yT = A^T yA
    spmm_pull_kernel<<<spmm_blk, 256, 0, stream>>>(row_ptr, csr_row_col, dp_out, dp_in, yB, yA, N);
    spmm_pull_kernel<<<spmm_blk, 256, 0, stream>>>(col_ptr, csr_col_row, dp_in, dp_out, yA, yT, N);
    gemm2_kernel<<<gblk, 256, 0, stream>>>(yA, yT, W_sd + 2 * 4096, W_ds + 2 * 4096,
                                           bias_tot, 0.125f, out, N, 0);
}

// Round 4
// 642.241 us; speedup vs baseline: 2.2770x; 1.4415x over previous
//
#include <hip/hip_runtime.h>
#include <hip/hip_bf16.h>

#define N_NODES 100000
#define N_EDGES 1600000
#define DF 64

#define BSHIFT 9                       // 512 nodes per bucket
#define NBUCK ((N_NODES + 511) >> 9)   // 196
#define NBPAD 256
#define CHUNK 8192
#define CAP 10240                      // LDS slice capacity (mean 8192, +22 sigma)

// ---------------- degree histogram ----------------
__global__ void hist_kernel(const int* __restrict__ row, const int* __restrict__ col,
                            int* __restrict__ deg_out, int* __restrict__ deg_in, int E) {
    int e = blockIdx.x * blockDim.x + threadIdx.x;
    if (e < E) {
        atomicAdd(&deg_out[row[e]], 1);
        atomicAdd(&deg_in[col[e]], 1);
    }
}

// ---------------- deg^-0.25 ----------------
__global__ void dpow_kernel(const int* __restrict__ deg_out, const int* __restrict__ deg_in,
                            float* __restrict__ dp_out, float* __restrict__ dp_in, int n) {
    int i = blockIdx.x * blockDim.x + threadIdx.x;
    if (i < n) {
        int a = deg_out[i];
        int b = deg_in[i];
        dp_out[i] = (a > 0) ? rsqrtf(sqrtf((float)a)) : 0.f;
        dp_in[i]  = (b > 0) ? rsqrtf(sqrtf((float)b)) : 0.f;
    }
}

// ---------------- scan: per-block partial sums ----------------
__global__ void scan_partial_kernel(const int* __restrict__ deg, int n, int* __restrict__ partial) {
    __shared__ int sdata[256];
    int idx = blockIdx.x * 256 + threadIdx.x;
    int v = (idx < n) ? deg[idx] : 0;
    sdata[threadIdx.x] = v;
    __syncthreads();
    for (int s = 128; s > 0; s >>= 1) {
        if (threadIdx.x < s) sdata[threadIdx.x] += sdata[threadIdx.x + s];
        __syncthreads();
    }
    if (threadIdx.x == 0) partial[blockIdx.x] = sdata[0];
}

// ---------------- scan: exclusive scan of partials (single block, nblk <= 512) ----------------
__global__ void scan_mid_kernel(int* __restrict__ partial, int nblk) {
    __shared__ int s[512];
    int t = threadIdx.x;
    int v = (t < nblk) ? partial[t] : 0;
    s[t] = v;
    __syncthreads();
    for (int off = 1; off < 512; off <<= 1) {
        int add = (t >= off) ? s[t - off] : 0;
        __syncthreads();
        s[t] += add;
        __syncthreads();
    }
    if (t < nblk) partial[t] = s[t] - v;   // exclusive
}

// ---------------- scan: emit final ptr array ----------------
__global__ void scan_emit_kernel(const int* __restrict__ deg, const int* __restrict__ partial,
                                 int n, int* __restrict__ ptr) {
    __shared__ int buf[256];
    int t = threadIdx.x;
    int idx = blockIdx.x * 256 + t;
    int v = (idx < n) ? deg[idx] : 0;
    buf[t] = v;
    __syncthreads();
    for (int off = 1; off < 256; off <<= 1) {
        int add = (t >= off) ? buf[t - off] : 0;
        __syncthreads();
        buf[t] += add;
        __syncthreads();
    }
    int excl = buf[t] - v + partial[blockIdx.x];
    if (idx < n) ptr[idx] = excl;
    if (idx == n - 1) ptr[n] = excl + v;
}

// ---------------- bucket cursor init: cursor[b] = ptr[b*512] ----------------
__global__ void cursor_init_kernel(const int* __restrict__ rp, const int* __restrict__ cp,
                                   int* __restrict__ cur_r, int* __restrict__ cur_c) {
    int b = blockIdx.x * blockDim.x + threadIdx.x;
    if (b < NBUCK) {
        cur_r[b] = rp[b << BSHIFT];
        cur_c[b] = cp[b << BSHIFT];
    }
}

// ---------------- pass A: bucketize edges; all global writes are coalesced runs ----------------
__global__ __launch_bounds__(256) void bucket_scatter_kernel(
        const int* __restrict__ key, const int* __restrict__ other,
        int* __restrict__ cursors, unsigned int* __restrict__ staging, int E) {
    __shared__ unsigned int stage[CHUNK];
    __shared__ int lcount[NBPAD];
    __shared__ int lscan[NBPAD];
    __shared__ int lcur[NBPAD];
    __shared__ int gbase[NBPAD];
    int t = threadIdx.x;
    int e0 = blockIdx.x * CHUNK;
    lcount[t] = 0;
    lcur[t] = 0;
    __syncthreads();
    for (int i = t; i < CHUNK; i += 256) {
        int e = e0 + i;
        if (e < E) atomicAdd(&lcount[key[e] >> BSHIFT], 1);
    }
    __syncthreads();
    int v = lcount[t];
    lscan[t] = v;
    __syncthreads();
    for (int off = 1; off < 256; off <<= 1) {
        int add = (t >= off) ? lscan[t - off] : 0;
        __syncthreads();
        lscan[t] += add;
        __syncthreads();
    }
    int excl = lscan[t] - v;
    if (t < NBUCK && v > 0) gbase[t] = atomicAdd(&cursors[t], v);
    __syncthreads();
    lscan[t] = excl;
    __syncthreads();
    for (int i = t; i < CHUNK; i += 256) {
        int e = e0 + i;
        if (e < E) {
            int k = key[e], c = other[e];
            int b = k >> BSHIFT;
            int pos = lscan[b] + atomicAdd(&lcur[b], 1);
            stage[pos] = ((unsigned int)(k & 511) << 17) | (unsigned int)c;
        }
    }
    __syncthreads();
    int wave = t >> 6, lane = t & 63;
    for (int b = wave; b < NBUCK; b += 4) {
        int cnt = lcount[b];
        if (cnt == 0) continue;
        int lb = lscan[b], gb = gbase[b];
        for (int j = lane; j < cnt; j += 64) staging[gb + j] = stage[lb + j];
    }
}

// ---------------- pass B: per bucket, build CSR slice in LDS, write linearly ----------------
__global__ __launch_bounds__(256) void bucket_build_kernel(
        const int* __restrict__ ptr, const unsigned int* __restrict__ staging,
        int* __restrict__ csr, int n) {
    __shared__ int pb[513];
    __shared__ int cur[512];
    __shared__ int slice[CAP];
    int b = blockIdx.x, t = threadIdx.x;
    int lo = b << BSHIFT;
    int hi = min(n, lo + 512);
    int nn = hi - lo;
    for (int i = t; i <= nn; i += 256) pb[i] = ptr[lo + i];
    for (int i = t; i < 512; i += 256) cur[i] = 0;
    __syncthreads();
    int base = pb[0], S = pb[nn] - base;
    if (S <= CAP) {
        for (int i = t; i < S; i += 256) {
            unsigned int w = staging[base + i];
            int rl = (int)(w >> 17), c = (int)(w & 0x1FFFFu);
            int pos = (pb[rl] - base) + atomicAdd(&cur[rl], 1);
            slice[pos] = c;
        }
        __syncthreads();
        for (int i = t; i < S; i += 256) csr[base + i] = slice[i];
    } else {  // safety fallback
        for (int i = t; i < S; i += 256) {
            unsigned int w = staging[base + i];
            int rl = (int)(w >> 17), c = (int)(w & 0x1FFFFu);
            int pos = pb[rl] + atomicAdd(&cur[rl], 1);
            csr[pos] = c;
        }
    }
}

// ---------------- pull SpMM: wave = node; 4 edge-slots x 16 float4-lanes ----------------
__global__ __launch_bounds__(256) void spmm_pull_kernel(
        const int* __restrict__ ptr, const int* __restrict__ nbr,
        const float* __restrict__ dp_dst, const float* __restrict__ dp_src,
        const float* __restrict__ src, float* __restrict__ dst, int n) {
    int wid = (blockIdx.x * blockDim.x + threadIdx.x) >> 6;   // wave = node
    int lane = threadIdx.x & 63;
    if (wid >= n) return;
    int slot = lane >> 4;     // edge slot 0..3
    int d4   = lane & 15;     // float4 index within the 64-float row
    int beg = ptr[wid], end = ptr[wid + 1];
    float4 acc = {0.f, 0.f, 0.f, 0.f};
    for (int p = beg + slot; p < end; p += 4) {
        int c = nbr[p];
        float w = dp_src[c];
        const float4 v = *(const float4*)&src[(size_t)c * DF + d4 * 4];
        acc.x += w * v.x;
        acc.y += w * v.y;
        acc.z += w * v.z;
        acc.w += w * v.w;
    }
    acc.x += __shfl_xor(acc.x, 16);
    acc.y += __shfl_xor(acc.y, 16);
    acc.z += __shfl_xor(acc.z, 16);
    acc.w += __shfl_xor(acc.w, 16);
    acc.x += __shfl_xor(acc.x, 32);
    acc.y += __shfl_xor(acc.y, 32);
    acc.z += __shfl_xor(acc.z, 32);
    acc.w += __shfl_xor(acc.w, 32);
    if (slot == 0) {
        float s = dp_dst[wid];
        float4 o = { acc.x * s, acc.y * s, acc.z * s, acc.w * s };
        *(float4*)&dst[(size_t)wid * DF + d4 * 4] = o;
    }
}

// ---------------- final: out = 0.5*out + 0.5*(A^T z) + bias_tot ----------------
__global__ __launch_bounds__(256) void spmm_final_kernel(
        const int* __restrict__ ptr, const int* __restrict__ nbr,
        const float* __restrict__ dp_dst, const float* __restrict__ dp_src,
        const float* __restrict__ z, const float* __restrict__ bias_tot,
        float* __restrict__ out, int n) {
    int wid = (blockIdx.x * blockDim.x + threadIdx.x) >> 6;
    int lane = threadIdx.x & 63;
    if (wid >= n) return;
    int slot = lane >> 4;
    int d4   = lane & 15;
    int beg = ptr[wid], end = ptr[wid + 1];
    float4 acc = {0.f, 0.f, 0.f, 0.f};
    for (int p = beg + slot; p < end; p += 4) {
        int c = nbr[p];
        float w = dp_src[c];
        const float4 v = *(const float4*)&z[(size_t)c * DF + d4 * 4];
        acc.x += w * v.x;
        acc.y += w * v.y;
        acc.z += w * v.z;
        acc.w += w * v.w;
    }
    acc.x += __shfl_xor(acc.x, 16);
    acc.y += __shfl_xor(acc.y, 16);
    acc.z += __shfl_xor(acc.z, 16);
    acc.w += __shfl_xor(acc.w, 16);
    acc.x += __shfl_xor(acc.x, 32);
    acc.y += __shfl_xor(acc.y, 32);
    acc.z += __shfl_xor(acc.z, 32);
    acc.w += __shfl_xor(acc.w, 32);
    if (slot == 0) {
        float s = dp_dst[wid];
        float4 prev = *(float4*)&out[(size_t)wid * DF + d4 * 4];
        float4 bt = *(const float4*)&bias_tot[d4 * 4];
        float4 o;
        o.x = 0.5f * prev.x + 0.5f * s * acc.x + bt.x;
        o.y = 0.5f * prev.y + 0.5f * s * acc.y + bt.y;
        o.z = 0.5f * prev.z + 0.5f * s * acc.z + bt.z;
        o.w = 0.5f * prev.w + 0.5f * s * acc.w + bt.w;
        *(float4*)&out[(size_t)wid * DF + d4 * 4] = o;
    }
}

// ---------------- bias total (includes the alpha=0.5 factors) ----------------
__global__ void bias_total_kernel(const float* __restrict__ b_sd, const float* __restrict__ b_ds,
                                  float* __restrict__ bias_tot) {
    int o = threadIdx.x;   // 64 threads
    float s = 0.f, sc = 1.f;
    for (int i = 0; i < 3; ++i) {
        s += sc * (0.5f * b_sd[i * 64 + o] + 0.5f * b_ds[i * 64 + o]);
        sc *= 0.5f;
    }
    bias_tot[o] = s;
}

// ---------------- dual GEMM, shared Y: outA (+)= coef*Y*Wa^T ; outB (+)= coef*Y*Wb^T ----------------
__global__ __launch_bounds__(256) void gemm_dual_kernel(
        const float* __restrict__ Y,
        const float* __restrict__ Wa, const float* __restrict__ Wb,
        float coef, float* __restrict__ outA, float* __restrict__ outB, int n) {
    __shared__ float Was[64 * 65];
    __shared__ float Wbs[64 * 65];
    __shared__ float Ys[64 * 65];
    int t = threadIdx.x;
    int node0 = blockIdx.x * 64;
    for (int i = t; i < 1024; i += 256) {
        int r = i >> 4, c4 = (i & 15) * 4;
        float4 wa = ((const float4*)Wa)[i];
        float4 wb = ((const float4*)Wb)[i];
        Was[r * 65 + c4 + 0] = wa.x; Was[r * 65 + c4 + 1] = wa.y;
        Was[r * 65 + c4 + 2] = wa.z; Was[r * 65 + c4 + 3] = wa.w;
        Wbs[r * 65 + c4 + 0] = wb.x; Wbs[r * 65 + c4 + 1] = wb.y;
        Wbs[r * 65 + c4 + 2] = wb.z; Wbs[r * 65 + c4 + 3] = wb.w;
        int nd = node0 + r;
        float4 y = {0, 0, 0, 0};
        if (nd < n) y = *(const float4*)&Y[(size_t)nd * DF + c4];
        Ys[r * 65 + c4 + 0] = y.x; Ys[r * 65 + c4 + 1] = y.y;
        Ys[r * 65 + c4 + 2] = y.z; Ys[r * 65 + c4 + 3] = y.w;
    }
    __syncthreads();
    int tx = t & 15, ty = t >> 4;
    float accA[4][4] = {};
    float accB[4][4] = {};
    const float* yp = &Ys[(ty * 4) * 65];
    const float* wap = &Was[(tx * 4) * 65];
    const float* wbp = &Wbs[(tx * 4) * 65];
    for (int k = 0; k < 64; ++k) {
        float y[4], wa[4], wb[4];
#pragma unroll
        for (int i = 0; i < 4; ++i) y[i] = yp[i * 65 + k];
#pragma unroll
        for (int j = 0; j < 4; ++j) { wa[j] = wap[j * 65 + k]; wb[j] = wbp[j * 65 + k]; }
#pragma unroll
        for (int i = 0; i < 4; ++i)
#pragma unroll
            for (int j = 0; j < 4; ++j) {
                accA[i][j] += y[i] * wa[j];
                accB[i][j] += y[i] * wb[j];
            }
    }
#pragma unroll
    for (int i = 0; i < 4; ++i) {
        int nd = node0 + ty * 4 + i;
        if (nd < n) {
            float4* pa  = (float4*)&outA[(size_t)nd * DF + tx * 4];
            float4* pbp = (float4*)&outB[(size_t)nd * DF + tx * 4];
            float4 va = *pa, vb = *pbp;
            va.x += coef * accA[i][0]; va.y += coef * accA[i][1];
            va.z += coef * accA[i][2]; va.w += coef * accA[i][3];
            vb.x += coef * accB[i][0]; vb.y += coef * accB[i][1];
            vb.z += coef * accB[i][2]; vb.w += coef * accB[i][3];
            *pa = va;
            *pbp = vb;
        }
    }
}

// ---------------- dual GEMM, separate Y per branch (level 0, overwrites):
//   outA = YA*Wa^T ; outB = YB*Wb^T
__global__ __launch_bounds__(256) void gemm_dual2_kernel(
        const float* __restrict__ YA, const float* __restrict__ YB,
        const float* __restrict__ Wa, const float* __restrict__ Wb,
        float* __restrict__ outA, float* __restrict__ outB, int n) {
    __shared__ float Was[64 * 65];
    __shared__ float Wbs[64 * 65];
    __shared__ float Yas[64 * 65];
    __shared__ float Ybs[64 * 65];
    int t = threadIdx.x;
    int node0 = blockIdx.x * 64;
    for (int i = t; i < 1024; i += 256) {
        int r = i >> 4, c4 = (i & 15) * 4;
        float4 wa = ((const float4*)Wa)[i];
        float4 wb = ((const float4*)Wb)[i];
        Was[r * 65 + c4 + 0] = wa.x; Was[r * 65 + c4 + 1] = wa.y;
        Was[r * 65 + c4 + 2] = wa.z; Was[r * 65 + c4 + 3] = wa.w;
        Wbs[r * 65 + c4 + 0] = wb.x; Wbs[r * 65 + c4 + 1] = wb.y;
        Wbs[r * 65 + c4 + 2] = wb.z; Wbs[r * 65 + c4 + 3] = wb.w;
        int nd = node0 + r;
        float4 ya = {0,0,0,0}, yb = {0,0,0,0};
        if (nd < n) {
            ya = *(const float4*)&YA[(size_t)nd * DF + c4];
            yb = *(const float4*)&YB[(size_t)nd * DF + c4];
        }
        Yas[r * 65 + c4 + 0] = ya.x; Yas[r * 65 + c4 + 1] = ya.y;
        Yas[r * 65 + c4 + 2] = ya.z; Yas[r * 65 + c4 + 3] = ya.w;
        Ybs[r * 65 + c4 + 0] = yb.x; Ybs[r * 65 + c4 + 1] = yb.y;
        Ybs[r * 65 + c4 + 2] = yb.z; Ybs[r * 65 + c4 + 3] = yb.w;
    }
    __syncthreads();
    int tx = t & 15, ty = t >> 4;
    float accA[4][4] = {};
    float accB[4][4] = {};
    const float* yap = &Yas[(ty * 4) * 65];
    const float* ybp = &Ybs[(ty * 4) * 65];
    const float* wap = &Was[(tx * 4) * 65];
    const float* wbp = &Wbs[(tx * 4) * 65];
    for (int k = 0; k < 64; ++k) {
        float ya[4], yb[4], wa[4], wb[4];
#pragma unroll
        for (int i = 0; i < 4; ++i) { ya[i] = yap[i * 65 + k]; yb[i] = ybp[i * 65 + k]; }
#pragma unroll
        for (int j = 0; j < 4; ++j) { wa[j] = wap[j * 65 + k]; wb[j] = wbp[j * 65 + k]; }
#pragma unroll
        for (int i = 0; i < 4; ++i)
#pragma unroll
            for (int j = 0; j < 4; ++j) {
                accA[i][j] += ya[i] * wa[j];
                accB[i][j] += yb[i] * wb[j];
            }
    }
#pragma unroll
    for (int i = 0; i < 4; ++i) {
        int nd = node0 + ty * 4 + i;
        if (nd < n) {
            float4 va = { accA[i][0], accA[i][1], accA[i][2], accA[i][3] };
            float4 vb = { accB[i][0], accB[i][1], accB[i][2], accB[i][3] };
            *(float4*)&outA[(size_t)nd * DF + tx * 4] = va;
            *(float4*)&outB[(size_t)nd * DF + tx * 4] = vb;
        }
    }
}

extern "C" void kernel_launch(void* const* d_in, const int* in_sizes, int n_in,
                              void* d_out, int out_size, void* d_ws, size_t ws_size,
                              hipStream_t stream) {
    const int N = N_NODES, E = N_EDGES;
    const float* x    = (const float*)d_in[0];
    const int*   ei   = (const int*)d_in[1];
    const int*   row  = ei;
    const int*   col  = ei + E;
    const float* W_sd = (const float*)d_in[2];
    const float* b_sd = (const float*)d_in[3];
    const float* W_ds = (const float*)d_in[4];
    const float* b_ds = (const float*)d_in[5];
    float* out = (float*)d_out;

    char* ws = (char*)d_ws;
    size_t off = 0;
    auto alloc = [&](size_t bytes) -> void* {
        void* p = ws + off;
        off += (bytes + 255) & ~(size_t)255;
        return p;
    };
    int*   deg_out = (int*)alloc((size_t)N * 4);
    int*   deg_in  = (int*)alloc((size_t)N * 4);
    int*   row_ptr = (int*)alloc((size_t)(N + 1) * 4);
    int*   col_ptr = (int*)alloc((size_t)(N + 1) * 4);
    int*   part_a  = (int*)alloc(512 * 4);
    int*   part_b  = (int*)alloc(512 * 4);
    float* dp_out  = (float*)alloc((size_t)N * 4);
    float* dp_in   = (float*)alloc((size_t)N * 4);
    int*   cur_r   = (int*)alloc((size_t)NBUCK * 4);
    int*   cur_c   = (int*)alloc((size_t)NBUCK * 4);
    int*   csr_row_col = (int*)alloc((size_t)E * 4);
    int*   csr_col_row = (int*)alloc((size_t)E * 4);
    float* bias_tot = (float*)alloc(64 * 4);
    float* yA = (float*)alloc((size_t)N * DF * 4);
    float* yB = (float*)alloc((size_t)N * DF * 4);
    float* z  = (float*)alloc((size_t)N * DF * 4);
    // staging buffers overlay yA/yB: used strictly before any y write
    unsigned int* stg_r = (unsigned int*)yA;
    unsigned int* stg_c = (unsigned int*)yB;

    hipMemsetAsync(deg_out, 0, (size_t)N * 4, stream);
    hipMemsetAsync(deg_in,  0, (size_t)N * 4, stream);

    const int eblk = (E + 255) / 256;
    const int nblk = (N + 255) / 256;          // 391
    hist_kernel<<<eblk, 256, 0, stream>>>(row, col, deg_out, deg_in, E);
    dpow_kernel<<<nblk, 256, 0, stream>>>(deg_out, deg_in, dp_out, dp_in, N);

    // exclusive-scan degree -> ptr arrays
    scan_partial_kernel<<<nblk, 256, 0, stream>>>(deg_out, N, part_a);
    scan_mid_kernel<<<1, 512, 0, stream>>>(part_a, nblk);
    scan_emit_kernel<<<nblk, 256, 0, stream>>>(deg_out, part_a, N, row_ptr);
    scan_partial_kernel<<<nblk, 256, 0, stream>>>(deg_in, N, part_b);
    scan_mid_kernel<<<1, 512, 0, stream>>>(part_b, nblk);
    scan_emit_kernel<<<nblk, 256, 0, stream>>>(deg_in, part_b, N, col_ptr);

    // bucketed CSR build (coalesced writes only)
    cursor_init_kernel<<<1, 256, 0, stream>>>(row_ptr, col_ptr, cur_r, cur_c);
    const int ablk = (E + CHUNK - 1) / CHUNK;  // 196
    bucket_scatter_kernel<<<ablk, 256, 0, stream>>>(row, col, cur_r, stg_r, E);
    bucket_scatter_kernel<<<ablk, 256, 0, stream>>>(col, row, cur_c, stg_c, E);
    bucket_build_kernel<<<NBUCK, 256, 0, stream>>>(row_ptr, stg_r, csr_row_col, N);
    bucket_build_kernel<<<NBUCK, 256, 0, stream>>>(col_ptr, stg_c, csr_col_row, N);

    bias_total_kernel<<<1, 64, 0, stream>>>(b_sd, b_ds, bias_tot);

    const int spmm_blk = (N * 64 + 255) / 256;
    const int gblk = (N + 63) / 64;

    // chain: y0 = A x ; y1 = A y0 ; y2 = A y1
    // out = sum scale_i * y_i * Wsd_i^T
    // z   = x*Wds0^T + 0.5*y1*Wds1^T + 0.25*y2*Wds2^T   (note level-0 operand is x!)
    spmm_pull_kernel<<<spmm_blk, 256, 0, stream>>>(row_ptr, csr_row_col, dp_out, dp_in, x, yA, N);
    gemm_dual2_kernel<<<gblk, 256, 0, stream>>>(yA, x, W_sd + 0 * 4096, W_ds + 0 * 4096,
                                                out, z, N);
    spmm_pull_kernel<<<spmm_blk, 256, 0, stream>>>(row_ptr, csr_row_col, dp_out, dp_in, yA, yB, N);
    gemm_dual_kernel<<<gblk, 256, 0, stream>>>(yB, W_sd + 1 * 4096, W_ds + 1 * 4096,
                                               0.5f, out, z, N);
    spmm_pull_kernel<<<spmm_blk, 256, 0, stream>>>(row_ptr, csr_row_col, dp_out, dp_in, yB, yA, N);
    gemm_dual_kernel<<<gblk, 256, 0, stream>>>(yA, W_sd + 2 * 4096, W_ds + 2 * 4096,
                                               0.25f, out, z, N);

    // out = 0.5*out + 0.5*(A^T z) + bias_tot
    spmm_final_kernel<<<spmm_blk, 256, 0, stream>>>(col_ptr, csr_col_row, dp_in, dp_out,
                                                    z, bias_tot, out, N);
}

// Round 5
// 521.964 us; speedup vs baseline: 2.8017x; 1.2304x over previous
//
#include <hip/hip_runtime.h>
#include <hip/hip_bf16.h>

#define N_NODES 100000
#define N_EDGES 1600000
#define DF 64

#define BSHIFT 9                       // 512 nodes per bucket
#define NBUCK ((N_NODES + 511) >> 9)   // 196
#define NBPAD 256
#define CHUNK 8192
#define CAP 10240                      // LDS slice capacity (mean 8192, +22 sigma)

// ---------------- bucket count: per-block LDS histogram of buckets, both directions ----------------
__global__ __launch_bounds__(256) void bucket_count_kernel(
        const int* __restrict__ row, const int* __restrict__ col,
        int* __restrict__ cnt_r, int* __restrict__ cnt_c, int E) {
    __shared__ int lr[NBPAD];
    __shared__ int lc[NBPAD];
    int t = threadIdx.x;
    lr[t] = 0; lc[t] = 0;
    __syncthreads();
    int e0 = blockIdx.x * CHUNK;
    for (int i = t; i < CHUNK; i += 256) {
        int e = e0 + i;
        if (e < E) {
            atomicAdd(&lr[row[e] >> BSHIFT], 1);
            atomicAdd(&lc[col[e] >> BSHIFT], 1);
        }
    }
    __syncthreads();
    int vr = lr[t], vc = lc[t];
    if (vr) atomicAdd(&cnt_r[t], vr);
    if (vc) atomicAdd(&cnt_c[t], vc);
}

// ---------------- bucket scan: excl-scan bucket totals -> bases + scatter cursors ----------------
__global__ void bucket_scan_kernel(const int* __restrict__ cnt_r, const int* __restrict__ cnt_c,
                                   int* __restrict__ base_r, int* __restrict__ base_c,
                                   int* __restrict__ cur_r, int* __restrict__ cur_c) {
    __shared__ int s[256];
    int t = threadIdx.x;
    int v = (t < NBUCK) ? cnt_r[t] : 0;
    s[t] = v; __syncthreads();
    for (int off = 1; off < 256; off <<= 1) {
        int a = (t >= off) ? s[t - off] : 0; __syncthreads();
        s[t] += a; __syncthreads();
    }
    if (t < NBUCK) { base_r[t] = s[t] - v; cur_r[t] = s[t] - v; }
    if (t == NBUCK - 1) base_r[NBUCK] = s[t];
    __syncthreads();
    int v2 = (t < NBUCK) ? cnt_c[t] : 0;
    s[t] = v2; __syncthreads();
    for (int off = 1; off < 256; off <<= 1) {
        int a = (t >= off) ? s[t - off] : 0; __syncthreads();
        s[t] += a; __syncthreads();
    }
    if (t < NBUCK) { base_c[t] = s[t] - v2; cur_c[t] = s[t] - v2; }
    if (t == NBUCK - 1) base_c[NBUCK] = s[t];
}

// ---------------- pass A: bucketize edges; all global writes are coalesced runs ----------------
__global__ __launch_bounds__(256) void bucket_scatter_kernel(
        const int* __restrict__ key, const int* __restrict__ other,
        int* __restrict__ cursors, unsigned int* __restrict__ staging, int E) {
    __shared__ unsigned int stage[CHUNK];
    __shared__ int lcount[NBPAD];
    __shared__ int lscan[NBPAD];
    __shared__ int lcur[NBPAD];
    __shared__ int gbase[NBPAD];
    int t = threadIdx.x;
    int e0 = blockIdx.x * CHUNK;
    lcount[t] = 0;
    lcur[t] = 0;
    __syncthreads();
    for (int i = t; i < CHUNK; i += 256) {
        int e = e0 + i;
        if (e < E) atomicAdd(&lcount[key[e] >> BSHIFT], 1);
    }
    __syncthreads();
    int v = lcount[t];
    lscan[t] = v;
    __syncthreads();
    for (int off = 1; off < 256; off <<= 1) {
        int add = (t >= off) ? lscan[t - off] : 0;
        __syncthreads();
        lscan[t] += add;
        __syncthreads();
    }
    int excl = lscan[t] - v;
    if (t < NBUCK && v > 0) gbase[t] = atomicAdd(&cursors[t], v);
    __syncthreads();
    lscan[t] = excl;
    __syncthreads();
    for (int i = t; i < CHUNK; i += 256) {
        int e = e0 + i;
        if (e < E) {
            int k = key[e], c = other[e];
            int b = k >> BSHIFT;
            int pos = lscan[b] + atomicAdd(&lcur[b], 1);
            stage[pos] = ((unsigned int)(k & 511) << 17) | (unsigned int)c;
        }
    }
    __syncthreads();
    int wave = t >> 6, lane = t & 63;
    for (int b = wave; b < NBUCK; b += 4) {
        int cnt = lcount[b];
        if (cnt == 0) continue;
        int lb = lscan[b], gb = gbase[b];
        for (int j = lane; j < cnt; j += 64) staging[gb + j] = stage[lb + j];
    }
}

// ---------------- per bucket: LDS degree histogram -> ptr slice + dp, all writes linear ----------------
__global__ __launch_bounds__(512) void bucket_degptr_kernel(
        const int* __restrict__ base, const unsigned int* __restrict__ staging,
        int* __restrict__ ptr, float* __restrict__ dp, int n) {
    __shared__ int cnt[512];
    __shared__ int sc[512];
    int b = blockIdx.x, t = threadIdx.x;
    int lo = b << BSHIFT;
    int nn = min(n - lo, 512);
    cnt[t] = 0;
    __syncthreads();
    int s0 = base[b], s1 = base[b + 1];
    for (int i = s0 + t; i < s1; i += 512)
        atomicAdd(&cnt[staging[i] >> 17], 1);
    __syncthreads();
    int v = cnt[t];
    sc[t] = v;
    __syncthreads();
    for (int off = 1; off < 512; off <<= 1) {
        int a = (t >= off) ? sc[t - off] : 0;
        __syncthreads();
        sc[t] += a;
        __syncthreads();
    }
    if (t < nn) {
        ptr[lo + t] = s0 + sc[t] - v;                       // exclusive
        dp[lo + t] = (v > 0) ? rsqrtf(sqrtf((float)v)) : 0.f;
    }
    if (lo + t == n - 1) ptr[n] = s0 + sc[t];              // == E on last bucket
}

// ---------------- pass B: per bucket, build CSR slice in LDS, write linearly ----------------
__global__ __launch_bounds__(256) void bucket_build_kernel(
        const int* __restrict__ ptr, const unsigned int* __restrict__ staging,
        int* __restrict__ csr, int n) {
    __shared__ int pb[513];
    __shared__ int cur[512];
    __shared__ int slice[CAP];
    int b = blockIdx.x, t = threadIdx.x;
    int lo = b << BSHIFT;
    int hi = min(n, lo + 512);
    int nn = hi - lo;
    for (int i = t; i <= nn; i += 256) pb[i] = ptr[lo + i];
    for (int i = t; i < 512; i += 256) cur[i] = 0;
    __syncthreads();
    int base = pb[0], S = pb[nn] - base;
    if (S <= CAP) {
        for (int i = t; i < S; i += 256) {
            unsigned int w = staging[base + i];
            int rl = (int)(w >> 17), c = (int)(w & 0x1FFFFu);
            int pos = (pb[rl] - base) + atomicAdd(&cur[rl], 1);
            slice[pos] = c;
        }
        __syncthreads();
        for (int i = t; i < S; i += 256) csr[base + i] = slice[i];
    } else {  // safety fallback
        for (int i = t; i < S; i += 256) {
            unsigned int w = staging[base + i];
            int rl = (int)(w >> 17), c = (int)(w & 0x1FFFFu);
            int pos = pb[rl] + atomicAdd(&cur[rl], 1);
            csr[pos] = c;
        }
    }
}

// ---------------- pull SpMM: wave = node; 4 edge-slots x 16 float4-lanes ----------------
__global__ __launch_bounds__(256) void spmm_pull_kernel(
        const int* __restrict__ ptr, const int* __restrict__ nbr,
        const float* __restrict__ dp_dst, const float* __restrict__ dp_src,
        const float* __restrict__ src, float* __restrict__ dst, int n) {
    int wid = (blockIdx.x * blockDim.x + threadIdx.x) >> 6;   // wave = node
    int lane = threadIdx.x & 63;
    if (wid >= n) return;
    int slot = lane >> 4;     // edge slot 0..3
    int d4   = lane & 15;     // float4 index within the 64-float row
    int beg = ptr[wid], end = ptr[wid + 1];
    float4 acc = {0.f, 0.f, 0.f, 0.f};
    for (int p = beg + slot; p < end; p += 4) {
        int c = nbr[p];
        float w = dp_src[c];
        const float4 v = *(const float4*)&src[(size_t)c * DF + d4 * 4];
        acc.x += w * v.x;
        acc.y += w * v.y;
        acc.z += w * v.z;
        acc.w += w * v.w;
    }
    acc.x += __shfl_xor(acc.x, 16);
    acc.y += __shfl_xor(acc.y, 16);
    acc.z += __shfl_xor(acc.z, 16);
    acc.w += __shfl_xor(acc.w, 16);
    acc.x += __shfl_xor(acc.x, 32);
    acc.y += __shfl_xor(acc.y, 32);
    acc.z += __shfl_xor(acc.z, 32);
    acc.w += __shfl_xor(acc.w, 32);
    if (slot == 0) {
        float s = dp_dst[wid];
        float4 o = { acc.x * s, acc.y * s, acc.z * s, acc.w * s };
        *(float4*)&dst[(size_t)wid * DF + d4 * 4] = o;
    }
}

// ---------------- final: out = 0.5*out + 0.5*(A^T z) + bias_tot ----------------
__global__ __launch_bounds__(256) void spmm_final_kernel(
        const int* __restrict__ ptr, const int* __restrict__ nbr,
        const float* __restrict__ dp_dst, const float* __restrict__ dp_src,
        const float* __restrict__ z, const float* __restrict__ bias_tot,
        float* __restrict__ out, int n) {
    int wid = (blockIdx.x * blockDim.x + threadIdx.x) >> 6;
    int lane = threadIdx.x & 63;
    if (wid >= n) return;
    int slot = lane >> 4;
    int d4   = lane & 15;
    int beg = ptr[wid], end = ptr[wid + 1];
    float4 acc = {0.f, 0.f, 0.f, 0.f};
    for (int p = beg + slot; p < end; p += 4) {
        int c = nbr[p];
        float w = dp_src[c];
        const float4 v = *(const float4*)&z[(size_t)c * DF + d4 * 4];
        acc.x += w * v.x;
        acc.y += w * v.y;
        acc.z += w * v.z;
        acc.w += w * v.w;
    }
    acc.x += __shfl_xor(acc.x, 16);
    acc.y += __shfl_xor(acc.y, 16);
    acc.z += __shfl_xor(acc.z, 16);
    acc.w += __shfl_xor(acc.w, 16);
    acc.x += __shfl_xor(acc.x, 32);
    acc.y += __shfl_xor(acc.y, 32);
    acc.z += __shfl_xor(acc.z, 32);
    acc.w += __shfl_xor(acc.w, 32);
    if (slot == 0) {
        float s = dp_dst[wid];
        float4 prev = *(float4*)&out[(size_t)wid * DF + d4 * 4];
        float4 bt = *(const float4*)&bias_tot[d4 * 4];
        float4 o;
        o.x = 0.5f * prev.x + 0.5f * s * acc.x + bt.x;
        o.y = 0.5f * prev.y + 0.5f * s * acc.y + bt.y;
        o.z = 0.5f * prev.z + 0.5f * s * acc.z + bt.z;
        o.w = 0.5f * prev.w + 0.5f * s * acc.w + bt.w;
        *(float4*)&out[(size_t)wid * DF + d4 * 4] = o;
    }
}

// ---------------- bias total (includes the alpha=0.5 factors) ----------------
__global__ void bias_total_kernel(const float* __restrict__ b_sd, const float* __restrict__ b_ds,
                                  float* __restrict__ bias_tot) {
    int o = threadIdx.x;   // 64 threads
    float s = 0.f, sc = 1.f;
    for (int i = 0; i < 3; ++i) {
        s += sc * (0.5f * b_sd[i * 64 + o] + 0.5f * b_ds[i * 64 + o]);
        sc *= 0.5f;
    }
    bias_tot[o] = s;
}

// ---------------- dual GEMM, shared Y: outA (+)= coef*Y*Wa^T ; outB (+)= coef*Y*Wb^T ----------------
__global__ __launch_bounds__(256) void gemm_dual_kernel(
        const float* __restrict__ Y,
        const float* __restrict__ Wa, const float* __restrict__ Wb,
        float coef, float* __restrict__ outA, float* __restrict__ outB, int n) {
    __shared__ float Was[64 * 65];
    __shared__ float Wbs[64 * 65];
    __shared__ float Ys[64 * 65];
    int t = threadIdx.x;
    int node0 = blockIdx.x * 64;
    for (int i = t; i < 1024; i += 256) {
        int r = i >> 4, c4 = (i & 15) * 4;
        float4 wa = ((const float4*)Wa)[i];
        float4 wb = ((const float4*)Wb)[i];
        Was[r * 65 + c4 + 0] = wa.x; Was[r * 65 + c4 + 1] = wa.y;
        Was[r * 65 + c4 + 2] = wa.z; Was[r * 65 + c4 + 3] = wa.w;
        Wbs[r * 65 + c4 + 0] = wb.x; Wbs[r * 65 + c4 + 1] = wb.y;
        Wbs[r * 65 + c4 + 2] = wb.z; Wbs[r * 65 + c4 + 3] = wb.w;
        int nd = node0 + r;
        float4 y = {0, 0, 0, 0};
        if (nd < n) y = *(const float4*)&Y[(size_t)nd * DF + c4];
        Ys[r * 65 + c4 + 0] = y.x; Ys[r * 65 + c4 + 1] = y.y;
        Ys[r * 65 + c4 + 2] = y.z; Ys[r * 65 + c4 + 3] = y.w;
    }
    __syncthreads();
    int tx = t & 15, ty = t >> 4;
    float accA[4][4] = {};
    float accB[4][4] = {};
    const float* yp = &Ys[(ty * 4) * 65];
    const float* wap = &Was[(tx * 4) * 65];
    const float* wbp = &Wbs[(tx * 4) * 65];
    for (int k = 0; k < 64; ++k) {
        float y[4], wa[4], wb[4];
#pragma unroll
        for (int i = 0; i < 4; ++i) y[i] = yp[i * 65 + k];
#pragma unroll
        for (int j = 0; j < 4; ++j) { wa[j] = wap[j * 65 + k]; wb[j] = wbp[j * 65 + k]; }
#pragma unroll
        for (int i = 0; i < 4; ++i)
#pragma unroll
            for (int j = 0; j < 4; ++j) {
                accA[i][j] += y[i] * wa[j];
                accB[i][j] += y[i] * wb[j];
            }
    }
#pragma unroll
    for (int i = 0; i < 4; ++i) {
        int nd = node0 + ty * 4 + i;
        if (nd < n) {
            float4* pa  = (float4*)&outA[(size_t)nd * DF + tx * 4];
            float4* pbp = (float4*)&outB[(size_t)nd * DF + tx * 4];
            float4 va = *pa, vb = *pbp;
            va.x += coef * accA[i][0]; va.y += coef * accA[i][1];
            va.z += coef * accA[i][2]; va.w += coef * accA[i][3];
            vb.x += coef * accB[i][0]; vb.y += coef * accB[i][1];
            vb.z += coef * accB[i][2]; vb.w += coef * accB[i][3];
            *pa = va;
            *pbp = vb;
        }
    }
}

// ---------------- dual GEMM, separate Y per branch (level 0, overwrites):
//   outA = YA*Wa^T ; outB = YB*Wb^T
__global__ __launch_bounds__(256) void gemm_dual2_kernel(
        const float* __restrict__ YA, const float* __restrict__ YB,
        const float* __restrict__ Wa, const float* __restrict__ Wb,
        float* __restrict__ outA, float* __restrict__ outB, int n) {
    __shared__ float Was[64 * 65];
    __shared__ float Wbs[64 * 65];
    __shared__ float Yas[64 * 65];
    __shared__ float Ybs[64 * 65];
    int t = threadIdx.x;
    int node0 = blockIdx.x * 64;
    for (int i = t; i < 1024; i += 256) {
        int r = i >> 4, c4 = (i & 15) * 4;
        float4 wa = ((const float4*)Wa)[i];
        float4 wb = ((const float4*)Wb)[i];
        Was[r * 65 + c4 + 0] = wa.x; Was[r * 65 + c4 + 1] = wa.y;
        Was[r * 65 + c4 + 2] = wa.z; Was[r * 65 + c4 + 3] = wa.w;
        Wbs[r * 65 + c4 + 0] = wb.x; Wbs[r * 65 + c4 + 1] = wb.y;
        Wbs[r * 65 + c4 + 2] = wb.z; Wbs[r * 65 + c4 + 3] = wb.w;
        int nd = node0 + r;
        float4 ya = {0,0,0,0}, yb = {0,0,0,0};
        if (nd < n) {
            ya = *(const float4*)&YA[(size_t)nd * DF + c4];
            yb = *(const float4*)&YB[(size_t)nd * DF + c4];
        }
        Yas[r * 65 + c4 + 0] = ya.x; Yas[r * 65 + c4 + 1] = ya.y;
        Yas[r * 65 + c4 + 2] = ya.z; Yas[r * 65 + c4 + 3] = ya.w;
        Ybs[r * 65 + c4 + 0] = yb.x; Ybs[r * 65 + c4 + 1] = yb.y;
        Ybs[r * 65 + c4 + 2] = yb.z; Ybs[r * 65 + c4 + 3] = yb.w;
    }
    __syncthreads();
    int tx = t & 15, ty = t >> 4;
    float accA[4][4] = {};
    float accB[4][4] = {};
    const float* yap = &Yas[(ty * 4) * 65];
    const float* ybp = &Ybs[(ty * 4) * 65];
    const float* wap = &Was[(tx * 4) * 65];
    const float* wbp = &Wbs[(tx * 4) * 65];
    for (int k = 0; k < 64; ++k) {
        float ya[4], yb[4], wa[4], wb[4];
#pragma unroll
        for (int i = 0; i < 4; ++i) { ya[i] = yap[i * 65 + k]; yb[i] = ybp[i * 65 + k]; }
#pragma unroll
        for (int j = 0; j < 4; ++j) { wa[j] = wap[j * 65 + k]; wb[j] = wbp[j * 65 + k]; }
#pragma unroll
        for (int i = 0; i < 4; ++i)
#pragma unroll
            for (int j = 0; j < 4; ++j) {
                accA[i][j] += ya[i] * wa[j];
                accB[i][j] += yb[i] * wb[j];
            }
    }
#pragma unroll
    for (int i = 0; i < 4; ++i) {
        int nd = node0 + ty * 4 + i;
        if (nd < n) {
            float4 va = { accA[i][0], accA[i][1], accA[i][2], accA[i][3] };
            float4 vb = { accB[i][0], accB[i][1], accB[i][2], accB[i][3] };
            *(float4*)&outA[(size_t)nd * DF + tx * 4] = va;
            *(float4*)&outB[(size_t)nd * DF + tx * 4] = vb;
        }
    }
}

extern "C" void kernel_launch(void* const* d_in, const int* in_sizes, int n_in,
                              void* d_out, int out_size, void* d_ws, size_t ws_size,
                              hipStream_t stream) {
    const int N = N_NODES, E = N_EDGES;
    const float* x    = (const float*)d_in[0];
    const int*   ei   = (const int*)d_in[1];
    const int*   row  = ei;
    const int*   col  = ei + E;
    const float* W_sd = (const float*)d_in[2];
    const float* b_sd = (const float*)d_in[3];
    const float* W_ds = (const float*)d_in[4];
    const float* b_ds = (const float*)d_in[5];
    float* out = (float*)d_out;

    char* ws = (char*)d_ws;
    size_t off = 0;
    auto alloc = [&](size_t bytes) -> void* {
        void* p = ws + off;
        off += (bytes + 255) & ~(size_t)255;
        return p;
    };
    int*   cnt_r   = (int*)alloc((size_t)NBUCK * 4);
    int*   cnt_c   = (int*)alloc((size_t)NBUCK * 4);
    int*   base_r  = (int*)alloc((size_t)(NBUCK + 1) * 4);
    int*   base_c  = (int*)alloc((size_t)(NBUCK + 1) * 4);
    int*   cur_r   = (int*)alloc((size_t)NBUCK * 4);
    int*   cur_c   = (int*)alloc((size_t)NBUCK * 4);
    int*   row_ptr = (int*)alloc((size_t)(N + 1) * 4);
    int*   col_ptr = (int*)alloc((size_t)(N + 1) * 4);
    float* dp_out  = (float*)alloc((size_t)N * 4);
    float* dp_in   = (float*)alloc((size_t)N * 4);
    int*   csr_row_col = (int*)alloc((size_t)E * 4);
    int*   csr_col_row = (int*)alloc((size_t)E * 4);
    float* bias_tot = (float*)alloc(64 * 4);
    float* yA = (float*)alloc((size_t)N * DF * 4);
    float* yB = (float*)alloc((size_t)N * DF * 4);
    float* z  = (float*)alloc((size_t)N * DF * 4);
    // staging buffers overlay yA/yB: used strictly before any y write
    unsigned int* stg_r = (unsigned int*)yA;
    unsigned int* stg_c = (unsigned int*)yB;

    hipMemsetAsync(cnt_r, 0, (size_t)NBUCK * 4, stream);
    hipMemsetAsync(cnt_c, 0, (size_t)NBUCK * 4, stream);

    const int ablk = (E + CHUNK - 1) / CHUNK;  // 196
    bucket_count_kernel<<<ablk, 256, 0, stream>>>(row, col, cnt_r, cnt_c, E);
    bucket_scan_kernel<<<1, 256, 0, stream>>>(cnt_r, cnt_c, base_r, base_c, cur_r, cur_c);
    bucket_scatter_kernel<<<ablk, 256, 0, stream>>>(row, col, cur_r, stg_r, E);
    bucket_scatter_kernel<<<ablk, 256, 0, stream>>>(col, row, cur_c, stg_c, E);
    bucket_degptr_kernel<<<NBUCK, 512, 0, stream>>>(base_r, stg_r, row_ptr, dp_out, N);
    bucket_degptr_kernel<<<NBUCK, 512, 0, stream>>>(base_c, stg_c, col_ptr, dp_in, N);
    bucket_build_kernel<<<NBUCK, 256, 0, stream>>>(row_ptr, stg_r, csr_row_col, N);
    bucket_build_kernel<<<NBUCK, 256, 0, stream>>>(col_ptr, stg_c, csr_col_row, N);

    bias_total_kernel<<<1, 64, 0, stream>>>(b_sd, b_ds, bias_tot);

    const int spmm_blk = (N * 64 + 255) / 256;
    const int gblk = (N + 63) / 64;

    // chain: y0 = A x ; y1 = A y0 ; y2 = A y1
    // out = sum scale_i * y_i * Wsd_i^T
    // z   = x*Wds0^T + 0.5*y1*Wds1^T + 0.25*y2*Wds2^T   (level-0 z operand is x!)
    spmm_pull_kernel<<<spmm_blk, 256, 0, stream>>>(row_ptr, csr_row_col, dp_out, dp_in, x, yA, N);
    gemm_dual2_kernel<<<gblk, 256, 0, stream>>>(yA, x, W_sd + 0 * 4096, W_ds + 0 * 4096,
                                                out, z, N);
    spmm_pull_kernel<<<spmm_blk, 256, 0, stream>>>(row_ptr, csr_row_col, dp_out, dp_in, yA, yB, N);
    gemm_dual_kernel<<<gblk, 256, 0, stream>>>(yB, W_sd + 1 * 4096, W_ds + 1 * 4096,
                                               0.5f, out, z, N);
    spmm_pull_kernel<<<spmm_blk, 256, 0, stream>>>(row_ptr, csr_row_col, dp_out, dp_in, yB, yA, N);
    gemm_dual_kernel<<<gblk, 256, 0, stream>>>(yA, W_sd + 2 * 4096, W_ds + 2 * 4096,
                                               0.25f, out, z, N);

    // out = 0.5*out + 0.5*(A^T z) + bias_tot
    spmm_final_kernel<<<spmm_blk, 256, 0, stream>>>(col_ptr, csr_col_row, dp_in, dp_out,
                                                    z, bias_tot, out, N);
}

// Round 6
// 448.480 us; speedup vs baseline: 3.2607x; 1.1639x over previous
//
#include <hip/hip_runtime.h>
#include <hip/hip_bf16.h>

#define N_NODES 100000
#define N_EDGES 1600000
#define DF 64

#define BSHIFT 9                       // 512 nodes per bucket
#define NBUCK ((N_NODES + 511) >> 9)   // 196
#define NBPAD 256
#define CHUNK 8192
#define CAP 10240                      // LDS slice capacity (mean 8192, +22 sigma)

typedef unsigned int uint;
typedef unsigned short ushort;

__device__ __forceinline__ uint pack2_rne(float a, float b) {
    uint ua = __float_as_uint(a); ua = (ua + 0x7fffu + ((ua >> 16) & 1u)) >> 16;
    uint ub = __float_as_uint(b); ub = (ub + 0x7fffu + ((ub >> 16) & 1u)) >> 16;
    return ua | (ub << 16);
}

// ---------------- bucket count ----------------
__global__ __launch_bounds__(256) void bucket_count_kernel(
        const int* __restrict__ row, const int* __restrict__ col,
        int* __restrict__ cnt_r, int* __restrict__ cnt_c, int E) {
    __shared__ int lr[NBPAD];
    __shared__ int lc[NBPAD];
    int t = threadIdx.x;
    lr[t] = 0; lc[t] = 0;
    __syncthreads();
    int e0 = blockIdx.x * CHUNK;
    for (int i = t; i < CHUNK; i += 256) {
        int e = e0 + i;
        if (e < E) {
            atomicAdd(&lr[row[e] >> BSHIFT], 1);
            atomicAdd(&lc[col[e] >> BSHIFT], 1);
        }
    }
    __syncthreads();
    int vr = lr[t], vc = lc[t];
    if (vr) atomicAdd(&cnt_r[t], vr);
    if (vc) atomicAdd(&cnt_c[t], vc);
}

// ---------------- bucket scan ----------------
__global__ void bucket_scan_kernel(const int* __restrict__ cnt_r, const int* __restrict__ cnt_c,
                                   int* __restrict__ base_r, int* __restrict__ base_c,
                                   int* __restrict__ cur_r, int* __restrict__ cur_c) {
    __shared__ int s[256];
    int t = threadIdx.x;
    int v = (t < NBUCK) ? cnt_r[t] : 0;
    s[t] = v; __syncthreads();
    for (int off = 1; off < 256; off <<= 1) {
        int a = (t >= off) ? s[t - off] : 0; __syncthreads();
        s[t] += a; __syncthreads();
    }
    if (t < NBUCK) { base_r[t] = s[t] - v; cur_r[t] = s[t] - v; }
    if (t == NBUCK - 1) base_r[NBUCK] = s[t];
    __syncthreads();
    int v2 = (t < NBUCK) ? cnt_c[t] : 0;
    s[t] = v2; __syncthreads();
    for (int off = 1; off < 256; off <<= 1) {
        int a = (t >= off) ? s[t - off] : 0; __syncthreads();
        s[t] += a; __syncthreads();
    }
    if (t < NBUCK) { base_c[t] = s[t] - v2; cur_c[t] = s[t] - v2; }
    if (t == NBUCK - 1) base_c[NBUCK] = s[t];
}

// ---------------- pass A: bucketize ----------------
__global__ __launch_bounds__(256) void bucket_scatter_kernel(
        const int* __restrict__ key, const int* __restrict__ other,
        int* __restrict__ cursors, unsigned int* __restrict__ staging, int E) {
    __shared__ unsigned int stage[CHUNK];
    __shared__ int lcount[NBPAD];
    __shared__ int lscan[NBPAD];
    __shared__ int lcur[NBPAD];
    __shared__ int gbase[NBPAD];
    int t = threadIdx.x;
    int e0 = blockIdx.x * CHUNK;
    lcount[t] = 0;
    lcur[t] = 0;
    __syncthreads();
    for (int i = t; i < CHUNK; i += 256) {
        int e = e0 + i;
        if (e < E) atomicAdd(&lcount[key[e] >> BSHIFT], 1);
    }
    __syncthreads();
    int v = lcount[t];
    lscan[t] = v;
    __syncthreads();
    for (int off = 1; off < 256; off <<= 1) {
        int add = (t >= off) ? lscan[t - off] : 0;
        __syncthreads();
        lscan[t] += add;
        __syncthreads();
    }
    int excl = lscan[t] - v;
    if (t < NBUCK && v > 0) gbase[t] = atomicAdd(&cursors[t], v);
    __syncthreads();
    lscan[t] = excl;
    __syncthreads();
    for (int i = t; i < CHUNK; i += 256) {
        int e = e0 + i;
        if (e < E) {
            int k = key[e], c = other[e];
            int b = k >> BSHIFT;
            int pos = lscan[b] + atomicAdd(&lcur[b], 1);
            stage[pos] = ((unsigned int)(k & 511) << 17) | (unsigned int)c;
        }
    }
    __syncthreads();
    int wave = t >> 6, lane = t & 63;
    for (int b = wave; b < NBUCK; b += 4) {
        int cnt = lcount[b];
        if (cnt == 0) continue;
        int lb = lscan[b], gb = gbase[b];
        for (int j = lane; j < cnt; j += 64) staging[gb + j] = stage[lb + j];
    }
}

// ---------------- per bucket: degree hist -> ptr + dp ----------------
__global__ __launch_bounds__(512) void bucket_degptr_kernel(
        const int* __restrict__ base, const unsigned int* __restrict__ staging,
        int* __restrict__ ptr, float* __restrict__ dp, int n) {
    __shared__ int cnt[512];
    __shared__ int sc[512];
    int b = blockIdx.x, t = threadIdx.x;
    int lo = b << BSHIFT;
    int nn = min(n - lo, 512);
    cnt[t] = 0;
    __syncthreads();
    int s0 = base[b], s1 = base[b + 1];
    for (int i = s0 + t; i < s1; i += 512)
        atomicAdd(&cnt[staging[i] >> 17], 1);
    __syncthreads();
    int v = cnt[t];
    sc[t] = v;
    __syncthreads();
    for (int off = 1; off < 512; off <<= 1) {
        int a = (t >= off) ? sc[t - off] : 0;
        __syncthreads();
        sc[t] += a;
        __syncthreads();
    }
    if (t < nn) {
        ptr[lo + t] = s0 + sc[t] - v;
        dp[lo + t] = (v > 0) ? rsqrtf(sqrtf((float)v)) : 0.f;
    }
    if (lo + t == n - 1) ptr[n] = s0 + sc[t];
}

// ---------------- pass B: build CSR slice ----------------
__global__ __launch_bounds__(256) void bucket_build_kernel(
        const int* __restrict__ ptr, const unsigned int* __restrict__ staging,
        int* __restrict__ csr, int n) {
    __shared__ int pb[513];
    __shared__ int cur[512];
    __shared__ int slice[CAP];
    int b = blockIdx.x, t = threadIdx.x;
    int lo = b << BSHIFT;
    int hi = min(n, lo + 512);
    int nn = hi - lo;
    for (int i = t; i <= nn; i += 256) pb[i] = ptr[lo + i];
    for (int i = t; i < 512; i += 256) cur[i] = 0;
    __syncthreads();
    int base = pb[0], S = pb[nn] - base;
    if (S <= CAP) {
        for (int i = t; i < S; i += 256) {
            unsigned int w = staging[base + i];
            int rl = (int)(w >> 17), c = (int)(w & 0x1FFFFu);
            int pos = (pb[rl] - base) + atomicAdd(&cur[rl], 1);
            slice[pos] = c;
        }
        __syncthreads();
        for (int i = t; i < S; i += 256) csr[base + i] = slice[i];
    } else {
        for (int i = t; i < S; i += 256) {
            unsigned int w = staging[base + i];
            int rl = (int)(w >> 17), c = (int)(w & 0x1FFFFu);
            int pos = pb[rl] + atomicAdd(&cur[rl], 1);
            csr[pos] = c;
        }
    }
}

// ---------------- fp32 -> bf16 convert ----------------
__global__ __launch_bounds__(256) void cvt_bf16_kernel(const float* __restrict__ in,
                                                       uint* __restrict__ out, int n8) {
    int i = blockIdx.x * blockDim.x + threadIdx.x;   // one uint4 (8 bf16) per thread
    if (i < n8) {
        const float4 a = ((const float4*)in)[i * 2];
        const float4 b = ((const float4*)in)[i * 2 + 1];
        uint4 o;
        o.x = pack2_rne(a.x, a.y);
        o.y = pack2_rne(a.z, a.w);
        o.z = pack2_rne(b.x, b.y);
        o.w = pack2_rne(b.z, b.w);
        ((uint4*)out)[i] = o;
    }
}

// ---------------- bf16 pull SpMM: wave = node; 8 edge-slots x 8 lanes x 8 bf16 ----------------
__global__ __launch_bounds__(256) void spmm_bf16_kernel(
        const int* __restrict__ ptr, const int* __restrict__ nbr,
        const float* __restrict__ dp_dst, const float* __restrict__ dp_src,
        const ushort* __restrict__ src, ushort* __restrict__ dst, int n) {
    int wid = (blockIdx.x * blockDim.x + threadIdx.x) >> 6;
    int lane = threadIdx.x & 63;
    if (wid >= n) return;
    int slot = lane >> 3;     // 0..7
    int d8   = lane & 7;      // 8-bf16 group
    int beg = ptr[wid], end = ptr[wid + 1];
    float acc[8] = {};
    for (int p = beg + slot; p < end; p += 8) {
        int c = nbr[p];
        float w = dp_src[c];
        const uint4 u = *(const uint4*)&src[(size_t)c * DF + d8 * 8];
        acc[0] += w * __uint_as_float(u.x << 16);
        acc[1] += w * __uint_as_float(u.x & 0xffff0000u);
        acc[2] += w * __uint_as_float(u.y << 16);
        acc[3] += w * __uint_as_float(u.y & 0xffff0000u);
        acc[4] += w * __uint_as_float(u.z << 16);
        acc[5] += w * __uint_as_float(u.z & 0xffff0000u);
        acc[6] += w * __uint_as_float(u.w << 16);
        acc[7] += w * __uint_as_float(u.w & 0xffff0000u);
    }
#pragma unroll
    for (int m = 8; m <= 32; m <<= 1)
#pragma unroll
        for (int j = 0; j < 8; ++j) acc[j] += __shfl_xor(acc[j], m);
    if (slot == 0) {
        float s = dp_dst[wid];
        uint4 o;
        o.x = pack2_rne(acc[0] * s, acc[1] * s);
        o.y = pack2_rne(acc[2] * s, acc[3] * s);
        o.z = pack2_rne(acc[4] * s, acc[5] * s);
        o.w = pack2_rne(acc[6] * s, acc[7] * s);
        *(uint4*)&dst[(size_t)wid * DF + d8 * 8] = o;
    }
}

// ---------------- final: out = 0.5*out + 0.5*(A^T zb16) + bias_tot ----------------
__global__ __launch_bounds__(256) void spmm_final_kernel(
        const int* __restrict__ ptr, const int* __restrict__ nbr,
        const float* __restrict__ dp_dst, const float* __restrict__ dp_src,
        const ushort* __restrict__ z, const float* __restrict__ bias_tot,
        float* __restrict__ out, int n) {
    int wid = (blockIdx.x * blockDim.x + threadIdx.x) >> 6;
    int lane = threadIdx.x & 63;
    if (wid >= n) return;
    int slot = lane >> 3;
    int d8   = lane & 7;
    int beg = ptr[wid], end = ptr[wid + 1];
    float acc[8] = {};
    for (int p = beg + slot; p < end; p += 8) {
        int c = nbr[p];
        float w = dp_src[c];
        const uint4 u = *(const uint4*)&z[(size_t)c * DF + d8 * 8];
        acc[0] += w * __uint_as_float(u.x << 16);
        acc[1] += w * __uint_as_float(u.x & 0xffff0000u);
        acc[2] += w * __uint_as_float(u.y << 16);
        acc[3] += w * __uint_as_float(u.y & 0xffff0000u);
        acc[4] += w * __uint_as_float(u.z << 16);
        acc[5] += w * __uint_as_float(u.z & 0xffff0000u);
        acc[6] += w * __uint_as_float(u.w << 16);
        acc[7] += w * __uint_as_float(u.w & 0xffff0000u);
    }
#pragma unroll
    for (int m = 8; m <= 32; m <<= 1)
#pragma unroll
        for (int j = 0; j < 8; ++j) acc[j] += __shfl_xor(acc[j], m);
    if (slot == 0) {
        float s = dp_dst[wid];
        float* op = &out[(size_t)wid * DF + d8 * 8];
        float4 p0 = *(float4*)op;
        float4 p1 = *(float4*)(op + 4);
        const float4 b0 = *(const float4*)&bias_tot[d8 * 8];
        const float4 b1 = *(const float4*)&bias_tot[d8 * 8 + 4];
        p0.x = 0.5f * p0.x + 0.5f * s * acc[0] + b0.x;
        p0.y = 0.5f * p0.y + 0.5f * s * acc[1] + b0.y;
        p0.z = 0.5f * p0.z + 0.5f * s * acc[2] + b0.z;
        p0.w = 0.5f * p0.w + 0.5f * s * acc[3] + b0.w;
        p1.x = 0.5f * p1.x + 0.5f * s * acc[4] + b1.x;
        p1.y = 0.5f * p1.y + 0.5f * s * acc[5] + b1.y;
        p1.z = 0.5f * p1.z + 0.5f * s * acc[6] + b1.z;
        p1.w = 0.5f * p1.w + 0.5f * s * acc[7] + b1.w;
        *(float4*)op = p0;
        *(float4*)(op + 4) = p1;
    }
}

// ---------------- bias total (includes the alpha=0.5 factors) ----------------
__global__ void bias_total_kernel(const float* __restrict__ b_sd, const float* __restrict__ b_ds,
                                  float* __restrict__ bias_tot) {
    int o = threadIdx.x;
    float s = 0.f, sc = 1.f;
    for (int i = 0; i < 3; ++i) {
        s += sc * (0.5f * b_sd[i * 64 + o] + 0.5f * b_ds[i * 64 + o]);
        sc *= 0.5f;
    }
    bias_tot[o] = s;
}

// ---------------- stage bf16 Y tile into LDS (fp32, pitch 65) ----------------
__device__ __forceinline__ void stage_y_bf16(const ushort* __restrict__ Y, int node0, int n,
                                             float* Ys, int t) {
    for (int i = t; i < 512; i += 256) {          // 512 uint4 per 64x64-bf16 tile
        int r = i >> 3, g = (i & 7) * 8;
        int nd = node0 + r;
        uint4 u = {0, 0, 0, 0};
        if (nd < n) u = *(const uint4*)&Y[(size_t)nd * DF + g];
        float* d = &Ys[r * 65 + g];
        d[0] = __uint_as_float(u.x << 16);
        d[1] = __uint_as_float(u.x & 0xffff0000u);
        d[2] = __uint_as_float(u.y << 16);
        d[3] = __uint_as_float(u.y & 0xffff0000u);
        d[4] = __uint_as_float(u.z << 16);
        d[5] = __uint_as_float(u.z & 0xffff0000u);
        d[6] = __uint_as_float(u.w << 16);
        d[7] = __uint_as_float(u.w & 0xffff0000u);
    }
}

__device__ __forceinline__ void stage_w(const float* __restrict__ W, float* Ws, int t) {
    for (int i = t; i < 1024; i += 256) {
        int r = i >> 4, c4 = (i & 15) * 4;
        float4 w = ((const float4*)W)[i];
        Ws[r * 65 + c4 + 0] = w.x; Ws[r * 65 + c4 + 1] = w.y;
        Ws[r * 65 + c4 + 2] = w.z; Ws[r * 65 + c4 + 3] = w.w;
    }
}

// ---------------- dual GEMM, shared bf16 Y: outA += coef*Y*Wa^T ; zfp += coef*Y*Wb^T ----------------
__global__ __launch_bounds__(256) void gemm_dual_kernel(
        const ushort* __restrict__ Y,
        const float* __restrict__ Wa, const float* __restrict__ Wb,
        float coef, float* __restrict__ outA, float* __restrict__ zfp, int n) {
    __shared__ float Was[64 * 65];
    __shared__ float Wbs[64 * 65];
    __shared__ float Ys[64 * 65];
    int t = threadIdx.x;
    int node0 = blockIdx.x * 64;
    stage_w(Wa, Was, t);
    stage_w(Wb, Wbs, t);
    stage_y_bf16(Y, node0, n, Ys, t);
    __syncthreads();
    int tx = t & 15, ty = t >> 4;
    float accA[4][4] = {};
    float accB[4][4] = {};
    const float* yp = &Ys[(ty * 4) * 65];
    const float* wap = &Was[(tx * 4) * 65];
    const float* wbp = &Wbs[(tx * 4) * 65];
    for (int k = 0; k < 64; ++k) {
        float y[4], wa[4], wb[4];
#pragma unroll
        for (int i = 0; i < 4; ++i) y[i] = yp[i * 65 + k];
#pragma unroll
        for (int j = 0; j < 4; ++j) { wa[j] = wap[j * 65 + k]; wb[j] = wbp[j * 65 + k]; }
#pragma unroll
        for (int i = 0; i < 4; ++i)
#pragma unroll
            for (int j = 0; j < 4; ++j) {
                accA[i][j] += y[i] * wa[j];
                accB[i][j] += y[i] * wb[j];
            }
    }
#pragma unroll
    for (int i = 0; i < 4; ++i) {
        int nd = node0 + ty * 4 + i;
        if (nd < n) {
            float4* pa = (float4*)&outA[(size_t)nd * DF + tx * 4];
            float4* pz = (float4*)&zfp[(size_t)nd * DF + tx * 4];
            float4 va = *pa, vz = *pz;
            va.x += coef * accA[i][0]; va.y += coef * accA[i][1];
            va.z += coef * accA[i][2]; va.w += coef * accA[i][3];
            vz.x += coef * accB[i][0]; vz.y += coef * accB[i][1];
            vz.z += coef * accB[i][2]; vz.w += coef * accB[i][3];
            *pa = va;
            *pz = vz;
        }
    }
}

// ---------------- level-0 dual GEMM, separate bf16 Y per branch (overwrites) ----------------
__global__ __launch_bounds__(256) void gemm_dual2_kernel(
        const ushort* __restrict__ YA, const ushort* __restrict__ YB,
        const float* __restrict__ Wa, const float* __restrict__ Wb,
        float* __restrict__ outA, float* __restrict__ zfp, int n) {
    __shared__ float Was[64 * 65];
    __shared__ float Wbs[64 * 65];
    __shared__ float Yas[64 * 65];
    __shared__ float Ybs[64 * 65];
    int t = threadIdx.x;
    int node0 = blockIdx.x * 64;
    stage_w(Wa, Was, t);
    stage_w(Wb, Wbs, t);
    stage_y_bf16(YA, node0, n, Yas, t);
    stage_y_bf16(YB, node0, n, Ybs, t);
    __syncthreads();
    int tx = t & 15, ty = t >> 4;
    float accA[4][4] = {};
    float accB[4][4] = {};
    const float* yap = &Yas[(ty * 4) * 65];
    const float* ybp = &Ybs[(ty * 4) * 65];
    const float* wap = &Was[(tx * 4) * 65];
    const float* wbp = &Wbs[(tx * 4) * 65];
    for (int k = 0; k < 64; ++k) {
        float ya[4], yb[4], wa[4], wb[4];
#pragma unroll
        for (int i = 0; i < 4; ++i) { ya[i] = yap[i * 65 + k]; yb[i] = ybp[i * 65 + k]; }
#pragma unroll
        for (int j = 0; j < 4; ++j) { wa[j] = wap[j * 65 + k]; wb[j] = wbp[j * 65 + k]; }
#pragma unroll
        for (int i = 0; i < 4; ++i)
#pragma unroll
            for (int j = 0; j < 4; ++j) {
                accA[i][j] += ya[i] * wa[j];
                accB[i][j] += yb[i] * wb[j];
            }
    }
#pragma unroll
    for (int i = 0; i < 4; ++i) {
        int nd = node0 + ty * 4 + i;
        if (nd < n) {
            float4 va = { accA[i][0], accA[i][1], accA[i][2], accA[i][3] };
            float4 vz = { accB[i][0], accB[i][1], accB[i][2], accB[i][3] };
            *(float4*)&outA[(size_t)nd * DF + tx * 4] = va;
            *(float4*)&zfp[(size_t)nd * DF + tx * 4] = vz;
        }
    }
}

// ---------------- last-level dual GEMM: outA += coef*Y*Wa^T ; zb16 = bf16(zfp + coef*Y*Wb^T) ----------------
__global__ __launch_bounds__(256) void gemm_dual_last_kernel(
        const ushort* __restrict__ Y,
        const float* __restrict__ Wa, const float* __restrict__ Wb,
        float coef, float* __restrict__ outA, const float* __restrict__ zfp,
        ushort* __restrict__ zb, int n) {
    __shared__ float Was[64 * 65];
    __shared__ float Wbs[64 * 65];
    __shared__ float Ys[64 * 65];
    int t = threadIdx.x;
    int node0 = blockIdx.x * 64;
    stage_w(Wa, Was, t);
    stage_w(Wb, Wbs, t);
    stage_y_bf16(Y, node0, n, Ys, t);
    __syncthreads();
    int tx = t & 15, ty = t >> 4;
    float accA[4][4] = {};
    float accB[4][4] = {};
    const float* yp = &Ys[(ty * 4) * 65];
    const float* wap = &Was[(tx * 4) * 65];
    const float* wbp = &Wbs[(tx * 4) * 65];
    for (int k = 0; k < 64; ++k) {
        float y[4], wa[4], wb[4];
#pragma unroll
        for (int i = 0; i < 4; ++i) y[i] = yp[i * 65 + k];
#pragma unroll
        for (int j = 0; j < 4; ++j) { wa[j] = wap[j * 65 + k]; wb[j] = wbp[j * 65 + k]; }
#pragma unroll
        for (int i = 0; i < 4; ++i)
#pragma unroll
            for (int j = 0; j < 4; ++j) {
                accA[i][j] += y[i] * wa[j];
                accB[i][j] += y[i] * wb[j];
            }
    }
#pragma unroll
    for (int i = 0; i < 4; ++i) {
        int nd = node0 + ty * 4 + i;
        if (nd < n) {
            float4* pa = (float4*)&outA[(size_t)nd * DF + tx * 4];
            const float4 vz = *(const float4*)&zfp[(size_t)nd * DF + tx * 4];
            float4 va = *pa;
            va.x += coef * accA[i][0]; va.y += coef * accA[i][1];
            va.z += coef * accA[i][2]; va.w += coef * accA[i][3];
            *pa = va;
            float z0 = vz.x + coef * accB[i][0];
            float z1 = vz.y + coef * accB[i][1];
            float z2 = vz.z + coef * accB[i][2];
            float z3 = vz.w + coef * accB[i][3];
            uint2 o = { pack2_rne(z0, z1), pack2_rne(z2, z3) };
            *(uint2*)&zb[(size_t)nd * DF + tx * 4] = o;
        }
    }
}

extern "C" void kernel_launch(void* const* d_in, const int* in_sizes, int n_in,
                              void* d_out, int out_size, void* d_ws, size_t ws_size,
                              hipStream_t stream) {
    const int N = N_NODES, E = N_EDGES;
    const float* x    = (const float*)d_in[0];
    const int*   ei   = (const int*)d_in[1];
    const int*   row  = ei;
    const int*   col  = ei + E;
    const float* W_sd = (const float*)d_in[2];
    const float* b_sd = (const float*)d_in[3];
    const float* W_ds = (const float*)d_in[4];
    const float* b_ds = (const float*)d_in[5];
    float* out = (float*)d_out;

    char* ws = (char*)d_ws;
    size_t off = 0;
    auto alloc = [&](size_t bytes) -> void* {
        void* p = ws + off;
        off += (bytes + 255) & ~(size_t)255;
        return p;
    };
    int*   cnt_r   = (int*)alloc((size_t)NBUCK * 4);
    int*   cnt_c   = (int*)alloc((size_t)NBUCK * 4);
    int*   base_r  = (int*)alloc((size_t)(NBUCK + 1) * 4);
    int*   base_c  = (int*)alloc((size_t)(NBUCK + 1) * 4);
    int*   cur_r   = (int*)alloc((size_t)NBUCK * 4);
    int*   cur_c   = (int*)alloc((size_t)NBUCK * 4);
    int*   row_ptr = (int*)alloc((size_t)(N + 1) * 4);
    int*   col_ptr = (int*)alloc((size_t)(N + 1) * 4);
    float* dp_out  = (float*)alloc((size_t)N * 4);
    float* dp_in   = (float*)alloc((size_t)N * 4);
    int*   csr_row_col = (int*)alloc((size_t)E * 4);
    int*   csr_col_row = (int*)alloc((size_t)E * 4);
    float* bias_tot = (float*)alloc(64 * 4);
    float* zfp = (float*)alloc((size_t)N * DF * 4);
    ushort* x_bf = (ushort*)alloc((size_t)N * DF * 2);
    ushort* yA   = (ushort*)alloc((size_t)N * DF * 2);
    ushort* yB   = (ushort*)alloc((size_t)N * DF * 2);
    ushort* zb   = (ushort*)alloc((size_t)N * DF * 2);
    // staging buffers (E*4 = 6.4 MB each) overlay the bf16 y buffers (12.8 MB each):
    // used strictly before any y write
    unsigned int* stg_r = (unsigned int*)yA;
    unsigned int* stg_c = (unsigned int*)yB;

    hipMemsetAsync(cnt_r, 0, (size_t)NBUCK * 4, stream);
    hipMemsetAsync(cnt_c, 0, (size_t)NBUCK * 4, stream);

    const int ablk = (E + CHUNK - 1) / CHUNK;  // 196
    bucket_count_kernel<<<ablk, 256, 0, stream>>>(row, col, cnt_r, cnt_c, E);
    bucket_scan_kernel<<<1, 256, 0, stream>>>(cnt_r, cnt_c, base_r, base_c, cur_r, cur_c);
    bucket_scatter_kernel<<<ablk, 256, 0, stream>>>(row, col, cur_r, stg_r, E);
    bucket_scatter_kernel<<<ablk, 256, 0, stream>>>(col, row, cur_c, stg_c, E);
    bucket_degptr_kernel<<<NBUCK, 512, 0, stream>>>(base_r, stg_r, row_ptr, dp_out, N);
    bucket_degptr_kernel<<<NBUCK, 512, 0, stream>>>(base_c, stg_c, col_ptr, dp_in, N);
    bucket_build_kernel<<<NBUCK, 256, 0, stream>>>(row_ptr, stg_r, csr_row_col, N);
    bucket_build_kernel<<<NBUCK, 256, 0, stream>>>(col_ptr, stg_c, csr_col_row, N);

    bias_total_kernel<<<1, 64, 0, stream>>>(b_sd, b_ds, bias_tot);

    // x -> bf16 (after staging no longer needed? x_bf is its own buffer - safe anytime)
    const int n8 = N * DF / 8;
    cvt_bf16_kernel<<<(n8 + 255) / 256, 256, 0, stream>>>(x, (uint*)x_bf, n8);

    const int spmm_blk = (N * 64 + 255) / 256;
    const int gblk = (N + 63) / 64;

    // chain: y0 = A x ; y1 = A y0 ; y2 = A y1   (all bf16 payloads, fp32 accum)
    // out = sum scale_i * y_i * Wsd_i^T         (fp32)
    // z   = x*Wds0^T + 0.5*y1*Wds1^T + 0.25*y2*Wds2^T  (fp32 accum, bf16 emit at last level)
    spmm_bf16_kernel<<<spmm_blk, 256, 0, stream>>>(row_ptr, csr_row_col, dp_out, dp_in,
                                                   x_bf, yA, N);
    gemm_dual2_kernel<<<gblk, 256, 0, stream>>>(yA, x_bf, W_sd + 0 * 4096, W_ds + 0 * 4096,
                                                out, zfp, N);
    spmm_bf16_kernel<<<spmm_blk, 256, 0, stream>>>(row_ptr, csr_row_col, dp_out, dp_in,
                                                   yA, yB, N);
    gemm_dual_kernel<<<gblk, 256, 0, stream>>>(yB, W_sd + 1 * 4096, W_ds + 1 * 4096,
                                               0.5f, out, zfp, N);
    spmm_bf16_kernel<<<spmm_blk, 256, 0, stream>>>(row_ptr, csr_row_col, dp_out, dp_in,
                                                   yB, yA, N);
    gemm_dual_last_kernel<<<gblk, 256, 0, stream>>>(yA, W_sd + 2 * 4096, W_ds + 2 * 4096,
                                                    0.25f, out, zfp, zb, N);

    // out = 0.5*out + 0.5*(A^T zb) + bias_tot
    spmm_final_kernel<<<spmm_blk, 256, 0, stream>>>(col_ptr, csr_col_row, dp_in, dp_out,
                                                    zb, bias_tot, out, N);
}

// Round 7
// 344.637 us; speedup vs baseline: 4.2432x; 1.3013x over previous
//
#include <hip/hip_runtime.h>
#include <hip/hip_bf16.h>

#define N_NODES 100000
#define N_EDGES 1600000
#define DF 64

#define BSHIFT 9                       // 512 nodes per bucket
#define NBUCK ((N_NODES + 511) >> 9)   // 196
#define NBPAD 256
#define CHUNK 8192
#define CAP 10240                      // LDS slice capacity (mean 8192, +22 sigma)

typedef unsigned int uint;
typedef unsigned short ushort;
typedef __attribute__((ext_vector_type(8))) short short8;
typedef __attribute__((ext_vector_type(4))) float f32x4;

__device__ __forceinline__ uint pack2_rne(float a, float b) {
    uint ua = __float_as_uint(a); ua = (ua + 0x7fffu + ((ua >> 16) & 1u)) >> 16;
    uint ub = __float_as_uint(b); ub = (ub + 0x7fffu + ((ub >> 16) & 1u)) >> 16;
    return ua | (ub << 16);
}
__device__ __forceinline__ ushort pack1_rne(float a) {
    uint u = __float_as_uint(a);
    return (ushort)((u + 0x7fffu + ((u >> 16) & 1u)) >> 16);
}

// ---------------- bucket count ----------------
__global__ __launch_bounds__(256) void bucket_count_kernel(
        const int* __restrict__ row, const int* __restrict__ col,
        int* __restrict__ cnt_r, int* __restrict__ cnt_c, int E) {
    __shared__ int lr[NBPAD];
    __shared__ int lc[NBPAD];
    int t = threadIdx.x;
    lr[t] = 0; lc[t] = 0;
    __syncthreads();
    int e0 = blockIdx.x * CHUNK;
    for (int i = t; i < CHUNK; i += 256) {
        int e = e0 + i;
        if (e < E) {
            atomicAdd(&lr[row[e] >> BSHIFT], 1);
            atomicAdd(&lc[col[e] >> BSHIFT], 1);
        }
    }
    __syncthreads();
    int vr = lr[t], vc = lc[t];
    if (vr) atomicAdd(&cnt_r[t], vr);
    if (vc) atomicAdd(&cnt_c[t], vc);
}

// ---------------- bucket scan ----------------
__global__ void bucket_scan_kernel(const int* __restrict__ cnt_r, const int* __restrict__ cnt_c,
                                   int* __restrict__ base_r, int* __restrict__ base_c,
                                   int* __restrict__ cur_r, int* __restrict__ cur_c) {
    __shared__ int s[256];
    int t = threadIdx.x;
    int v = (t < NBUCK) ? cnt_r[t] : 0;
    s[t] = v; __syncthreads();
    for (int off = 1; off < 256; off <<= 1) {
        int a = (t >= off) ? s[t - off] : 0; __syncthreads();
        s[t] += a; __syncthreads();
    }
    if (t < NBUCK) { base_r[t] = s[t] - v; cur_r[t] = s[t] - v; }
    if (t == NBUCK - 1) base_r[NBUCK] = s[t];
    __syncthreads();
    int v2 = (t < NBUCK) ? cnt_c[t] : 0;
    s[t] = v2; __syncthreads();
    for (int off = 1; off < 256; off <<= 1) {
        int a = (t >= off) ? s[t - off] : 0; __syncthreads();
        s[t] += a; __syncthreads();
    }
    if (t < NBUCK) { base_c[t] = s[t] - v2; cur_c[t] = s[t] - v2; }
    if (t == NBUCK - 1) base_c[NBUCK] = s[t];
}

// ---------------- pass A: bucketize ----------------
__global__ __launch_bounds__(256) void bucket_scatter_kernel(
        const int* __restrict__ key, const int* __restrict__ other,
        int* __restrict__ cursors, unsigned int* __restrict__ staging, int E) {
    __shared__ unsigned int stage[CHUNK];
    __shared__ int lcount[NBPAD];
    __shared__ int lscan[NBPAD];
    __shared__ int lcur[NBPAD];
    __shared__ int gbase[NBPAD];
    int t = threadIdx.x;
    int e0 = blockIdx.x * CHUNK;
    lcount[t] = 0;
    lcur[t] = 0;
    __syncthreads();
    for (int i = t; i < CHUNK; i += 256) {
        int e = e0 + i;
        if (e < E) atomicAdd(&lcount[key[e] >> BSHIFT], 1);
    }
    __syncthreads();
    int v = lcount[t];
    lscan[t] = v;
    __syncthreads();
    for (int off = 1; off < 256; off <<= 1) {
        int add = (t >= off) ? lscan[t - off] : 0;
        __syncthreads();
        lscan[t] += add;
        __syncthreads();
    }
    int excl = lscan[t] - v;
    if (t < NBUCK && v > 0) gbase[t] = atomicAdd(&cursors[t], v);
    __syncthreads();
    lscan[t] = excl;
    __syncthreads();
    for (int i = t; i < CHUNK; i += 256) {
        int e = e0 + i;
        if (e < E) {
            int k = key[e], c = other[e];
            int b = k >> BSHIFT;
            int pos = lscan[b] + atomicAdd(&lcur[b], 1);
            stage[pos] = ((unsigned int)(k & 511) << 17) | (unsigned int)c;
        }
    }
    __syncthreads();
    int wave = t >> 6, lane = t & 63;
    for (int b = wave; b < NBUCK; b += 4) {
        int cnt = lcount[b];
        if (cnt == 0) continue;
        int lb = lscan[b], gb = gbase[b];
        for (int j = lane; j < cnt; j += 64) staging[gb + j] = stage[lb + j];
    }
}

// ---------------- per bucket: degree hist -> ptr + dp ----------------
__global__ __launch_bounds__(512) void bucket_degptr_kernel(
        const int* __restrict__ base, const unsigned int* __restrict__ staging,
        int* __restrict__ ptr, float* __restrict__ dp, int n) {
    __shared__ int cnt[512];
    __shared__ int sc[512];
    int b = blockIdx.x, t = threadIdx.x;
    int lo = b << BSHIFT;
    int nn = min(n - lo, 512);
    cnt[t] = 0;
    __syncthreads();
    int s0 = base[b], s1 = base[b + 1];
    for (int i = s0 + t; i < s1; i += 512)
        atomicAdd(&cnt[staging[i] >> 17], 1);
    __syncthreads();
    int v = cnt[t];
    sc[t] = v;
    __syncthreads();
    for (int off = 1; off < 512; off <<= 1) {
        int a = (t >= off) ? sc[t - off] : 0;
        __syncthreads();
        sc[t] += a;
        __syncthreads();
    }
    if (t < nn) {
        ptr[lo + t] = s0 + sc[t] - v;
        dp[lo + t] = (v > 0) ? rsqrtf(sqrtf((float)v)) : 0.f;
    }
    if (lo + t == n - 1) ptr[n] = s0 + sc[t];
}

// ---------------- pass B: build CSR slice ----------------
__global__ __launch_bounds__(256) void bucket_build_kernel(
        const int* __restrict__ ptr, const unsigned int* __restrict__ staging,
        int* __restrict__ csr, int n) {
    __shared__ int pb[513];
    __shared__ int cur[512];
    __shared__ int slice[CAP];
    int b = blockIdx.x, t = threadIdx.x;
    int lo = b << BSHIFT;
    int hi = min(n, lo + 512);
    int nn = hi - lo;
    for (int i = t; i <= nn; i += 256) pb[i] = ptr[lo + i];
    for (int i = t; i < 512; i += 256) cur[i] = 0;
    __syncthreads();
    int base = pb[0], S = pb[nn] - base;
    if (S <= CAP) {
        for (int i = t; i < S; i += 256) {
            unsigned int w = staging[base + i];
            int rl = (int)(w >> 17), c = (int)(w & 0x1FFFFu);
            int pos = (pb[rl] - base) + atomicAdd(&cur[rl], 1);
            slice[pos] = c;
        }
        __syncthreads();
        for (int i = t; i < S; i += 256) csr[base + i] = slice[i];
    } else {
        for (int i = t; i < S; i += 256) {
            unsigned int w = staging[base + i];
            int rl = (int)(w >> 17), c = (int)(w & 0x1FFFFu);
            int pos = pb[rl] + atomicAdd(&cur[rl], 1);
            csr[pos] = c;
        }
    }
}

// ---------------- fp32 -> bf16 convert ----------------
__global__ __launch_bounds__(256) void cvt_bf16_kernel(const float* __restrict__ in,
                                                       uint* __restrict__ out, int n8) {
    int i = blockIdx.x * blockDim.x + threadIdx.x;   // one uint4 (8 bf16) per thread
    if (i < n8) {
        const float4 a = ((const float4*)in)[i * 2];
        const float4 b = ((const float4*)in)[i * 2 + 1];
        uint4 o;
        o.x = pack2_rne(a.x, a.y);
        o.y = pack2_rne(a.z, a.w);
        o.z = pack2_rne(b.x, b.y);
        o.w = pack2_rne(b.z, b.w);
        ((uint4*)out)[i] = o;
    }
}

// ---------------- weight prep: Wb[m][o][d] = bf16(scale_m * W), m 0..2=Wsd, 3..5=Wds ----------------
__global__ __launch_bounds__(256) void prep_w_kernel(const float* __restrict__ Wsd,
                                                     const float* __restrict__ Wds,
                                                     ushort* __restrict__ Wb) {
    int i = blockIdx.x * blockDim.x + threadIdx.x;   // over 6*4096
    if (i >= 6 * 4096) return;
    int m = i >> 12, r = i & 4095;
    int lv = (m >= 3) ? (m - 3) : m;
    float scale = (lv == 0) ? 1.f : ((lv == 1) ? 0.5f : 0.25f);
    float v = ((m < 3) ? Wsd[lv * 4096 + r] : Wds[lv * 4096 + r]) * scale;
    Wb[i] = pack1_rne(v);
}

// ---------------- bf16 pull SpMM: wave = node; 8 edge-slots x 8 lanes x 8 bf16 ----------------
__global__ __launch_bounds__(256) void spmm_bf16_kernel(
        const int* __restrict__ ptr, const int* __restrict__ nbr,
        const float* __restrict__ dp_dst, const float* __restrict__ dp_src,
        const ushort* __restrict__ src, ushort* __restrict__ dst, int n) {
    int wid = (blockIdx.x * blockDim.x + threadIdx.x) >> 6;
    int lane = threadIdx.x & 63;
    if (wid >= n) return;
    int slot = lane >> 3;     // 0..7
    int d8   = lane & 7;      // 8-bf16 group
    int beg = ptr[wid], end = ptr[wid + 1];
    float acc[8] = {};
    for (int p = beg + slot; p < end; p += 8) {
        int c = nbr[p];
        float w = dp_src[c];
        const uint4 u = *(const uint4*)&src[(size_t)c * DF + d8 * 8];
        acc[0] += w * __uint_as_float(u.x << 16);
        acc[1] += w * __uint_as_float(u.x & 0xffff0000u);
        acc[2] += w * __uint_as_float(u.y << 16);
        acc[3] += w * __uint_as_float(u.y & 0xffff0000u);
        acc[4] += w * __uint_as_float(u.z << 16);
        acc[5] += w * __uint_as_float(u.z & 0xffff0000u);
        acc[6] += w * __uint_as_float(u.w << 16);
        acc[7] += w * __uint_as_float(u.w & 0xffff0000u);
    }
#pragma unroll
    for (int m = 8; m <= 32; m <<= 1)
#pragma unroll
        for (int j = 0; j < 8; ++j) acc[j] += __shfl_xor(acc[j], m);
    if (slot == 0) {
        float s = dp_dst[wid];
        uint4 o;
        o.x = pack2_rne(acc[0] * s, acc[1] * s);
        o.y = pack2_rne(acc[2] * s, acc[3] * s);
        o.z = pack2_rne(acc[4] * s, acc[5] * s);
        o.w = pack2_rne(acc[6] * s, acc[7] * s);
        *(uint4*)&dst[(size_t)wid * DF + d8 * 8] = o;
    }
}

// ---------------- final: out = 0.5*out + 0.5*(A^T zb16) + bias_tot ----------------
__global__ __launch_bounds__(256) void spmm_final_kernel(
        const int* __restrict__ ptr, const int* __restrict__ nbr,
        const float* __restrict__ dp_dst, const float* __restrict__ dp_src,
        const ushort* __restrict__ z, const float* __restrict__ bias_tot,
        float* __restrict__ out, int n) {
    int wid = (blockIdx.x * blockDim.x + threadIdx.x) >> 6;
    int lane = threadIdx.x & 63;
    if (wid >= n) return;
    int slot = lane >> 3;
    int d8   = lane & 7;
    int beg = ptr[wid], end = ptr[wid + 1];
    float acc[8] = {};
    for (int p = beg + slot; p < end; p += 8) {
        int c = nbr[p];
        float w = dp_src[c];
        const uint4 u = *(const uint4*)&z[(size_t)c * DF + d8 * 8];
        acc[0] += w * __uint_as_float(u.x << 16);
        acc[1] += w * __uint_as_float(u.x & 0xffff0000u);
        acc[2] += w * __uint_as_float(u.y << 16);
        acc[3] += w * __uint_as_float(u.y & 0xffff0000u);
        acc[4] += w * __uint_as_float(u.z << 16);
        acc[5] += w * __uint_as_float(u.z & 0xffff0000u);
        acc[6] += w * __uint_as_float(u.w << 16);
        acc[7] += w * __uint_as_float(u.w & 0xffff0000u);
    }
#pragma unroll
    for (int m = 8; m <= 32; m <<= 1)
#pragma unroll
        for (int j = 0; j < 8; ++j) acc[j] += __shfl_xor(acc[j], m);
    if (slot == 0) {
        float s = dp_dst[wid];
        float* op = &out[(size_t)wid * DF + d8 * 8];
        float4 p0 = *(float4*)op;
        float4 p1 = *(float4*)(op + 4);
        const float4 b0 = *(const float4*)&bias_tot[d8 * 8];
        const float4 b1 = *(const float4*)&bias_tot[d8 * 8 + 4];
        p0.x = 0.5f * p0.x + 0.5f * s * acc[0] + b0.x;
        p0.y = 0.5f * p0.y + 0.5f * s * acc[1] + b0.y;
        p0.z = 0.5f * p0.z + 0.5f * s * acc[2] + b0.z;
        p0.w = 0.5f * p0.w + 0.5f * s * acc[3] + b0.w;
        p1.x = 0.5f * p1.x + 0.5f * s * acc[4] + b1.x;
        p1.y = 0.5f * p1.y + 0.5f * s * acc[5] + b1.y;
        p1.z = 0.5f * p1.z + 0.5f * s * acc[6] + b1.z;
        p1.w = 0.5f * p1.w + 0.5f * s * acc[7] + b1.w;
        *(float4*)op = p0;
        *(float4*)(op + 4) = p1;
    }
}

// ---------------- bias total (includes the alpha=0.5 factors) ----------------
__global__ void bias_total_kernel(const float* __restrict__ b_sd, const float* __restrict__ b_ds,
                                  float* __restrict__ bias_tot) {
    int o = threadIdx.x;
    float s = 0.f, sc = 1.f;
    for (int i = 0; i < 3; ++i) {
        s += sc * (0.5f * b_sd[i * 64 + o] + 0.5f * b_ds[i * 64 + o]);
        sc *= 0.5f;
    }
    bias_tot[o] = s;
}

// ---------------- fused MFMA GEMM:
//   out = y0*Wb0^T + y1*Wb1^T + y2*Wb2^T          (scales folded into Wb)
//   zb  = bf16( x*Wb3^T + y1*Wb4^T + y2*Wb5^T )
// mfma_f32_16x16x32_bf16. A: row=lane&15, k=(lane>>4)*8+j. B: col=lane&15, same k.
// D: col=lane&15, row=(lane>>4)*4+reg.  W staged in LDS fragment-major (lane-linear, conflict-free).
__global__ __launch_bounds__(256) void gemm_fused_kernel(
        const ushort* __restrict__ y0, const ushort* __restrict__ y1,
        const ushort* __restrict__ y2, const ushort* __restrict__ xb,
        const ushort* __restrict__ Wb,
        float* __restrict__ out, ushort* __restrict__ zb, int n) {
    __shared__ ushort wlds[6 * 4096];
    int t = threadIdx.x;
    // stage: slot f (8 ushorts) = ((m*4+cb)*2+ks)*64 + lane
    //        src elem           = m*4096 + (16*cb + (f&15))*64 + ks*32 + ((f>>4)&3)*8
    for (int f = t; f < 3072; f += 256) {
        int c  = f & 15;
        int kq = (f >> 4) & 3;
        int ks = (f >> 6) & 1;
        int cb = (f >> 7) & 3;
        int m  = f >> 9;
        const uint4 v = *(const uint4*)&Wb[m * 4096 + (16 * cb + c) * 64 + ks * 32 + kq * 8];
        *(uint4*)&wlds[f * 8] = v;
    }
    __syncthreads();
    int w = t >> 6, lane = t & 63;
    int node0 = blockIdx.x * 64 + w * 16;
    int arow = node0 + (lane & 15);
    int kqo = (lane >> 4) * 8;
    f32x4 accO[4] = {};
    f32x4 accZ[4] = {};
#pragma unroll
    for (int ks = 0; ks < 2; ++ks) {
        int aoff = ks * 32 + kqo;
        short8 a0 = {}, a1 = {}, a2 = {}, ax = {};
        if (arow < n) {
            a0 = *(const short8*)&y0[(size_t)arow * DF + aoff];
            a1 = *(const short8*)&y1[(size_t)arow * DF + aoff];
            a2 = *(const short8*)&y2[(size_t)arow * DF + aoff];
            ax = *(const short8*)&xb[(size_t)arow * DF + aoff];
        }
#pragma unroll
        for (int cb = 0; cb < 4; ++cb) {
            const ushort* bp = &wlds[(((cb * 2 + ks) * 64) + lane) * 8];
            short8 b0 = *(const short8*)(bp);
            short8 b1 = *(const short8*)(bp + 4096);
            short8 b2 = *(const short8*)(bp + 8192);
            short8 b3 = *(const short8*)(bp + 12288);
            short8 b4 = *(const short8*)(bp + 16384);
            short8 b5 = *(const short8*)(bp + 20480);
            accO[cb] = __builtin_amdgcn_mfma_f32_16x16x32_bf16(a0, b0, accO[cb], 0, 0, 0);
            accO[cb] = __builtin_amdgcn_mfma_f32_16x16x32_bf16(a1, b1, accO[cb], 0, 0, 0);
            accO[cb] = __builtin_amdgcn_mfma_f32_16x16x32_bf16(a2, b2, accO[cb], 0, 0, 0);
            accZ[cb] = __builtin_amdgcn_mfma_f32_16x16x32_bf16(ax, b3, accZ[cb], 0, 0, 0);
            accZ[cb] = __builtin_amdgcn_mfma_f32_16x16x32_bf16(a1, b4, accZ[cb], 0, 0, 0);
            accZ[cb] = __builtin_amdgcn_mfma_f32_16x16x32_bf16(a2, b5, accZ[cb], 0, 0, 0);
        }
    }
#pragma unroll
    for (int cb = 0; cb < 4; ++cb) {
#pragma unroll
        for (int r = 0; r < 4; ++r) {
            int nd = node0 + (lane >> 4) * 4 + r;
            if (nd < n) {
                int o = cb * 16 + (lane & 15);
                out[(size_t)nd * DF + o] = accO[cb][r];
                zb[(size_t)nd * DF + o] = pack1_rne(accZ[cb][r]);
            }
        }
    }
}

extern "C" void kernel_launch(void* const* d_in, const int* in_sizes, int n_in,
                              void* d_out, int out_size, void* d_ws, size_t ws_size,
                              hipStream_t stream) {
    const int N = N_NODES, E = N_EDGES;
    const float* x    = (const float*)d_in[0];
    const int*   ei   = (const int*)d_in[1];
    const int*   row  = ei;
    const int*   col  = ei + E;
    const float* W_sd = (const float*)d_in[2];
    const float* b_sd = (const float*)d_in[3];
    const float* W_ds = (const float*)d_in[4];
    const float* b_ds = (const float*)d_in[5];
    float* out = (float*)d_out;

    char* ws = (char*)d_ws;
    size_t off = 0;
    auto alloc = [&](size_t bytes) -> void* {
        void* p = ws + off;
        off += (bytes + 255) & ~(size_t)255;
        return p;
    };
    int*   cnt_r   = (int*)alloc((size_t)NBUCK * 4);
    int*   cnt_c   = (int*)alloc((size_t)NBUCK * 4);
    int*   base_r  = (int*)alloc((size_t)(NBUCK + 1) * 4);
    int*   base_c  = (int*)alloc((size_t)(NBUCK + 1) * 4);
    int*   cur_r   = (int*)alloc((size_t)NBUCK * 4);
    int*   cur_c   = (int*)alloc((size_t)NBUCK * 4);
    int*   row_ptr = (int*)alloc((size_t)(N + 1) * 4);
    int*   col_ptr = (int*)alloc((size_t)(N + 1) * 4);
    float* dp_out  = (float*)alloc((size_t)N * 4);
    float* dp_in   = (float*)alloc((size_t)N * 4);
    int*   csr_row_col = (int*)alloc((size_t)E * 4);
    int*   csr_col_row = (int*)alloc((size_t)E * 4);
    float* bias_tot = (float*)alloc(64 * 4);
    ushort* Wb   = (ushort*)alloc((size_t)6 * 4096 * 2);
    ushort* x_bf = (ushort*)alloc((size_t)N * DF * 2);
    ushort* y0   = (ushort*)alloc((size_t)N * DF * 2);
    ushort* y1   = (ushort*)alloc((size_t)N * DF * 2);
    ushort* y2   = (ushort*)alloc((size_t)N * DF * 2);
    ushort* zb   = (ushort*)alloc((size_t)N * DF * 2);
    // staging buffers (E*4 = 6.4 MB) overlay the bf16 y buffers (12.8 MB):
    // staging is consumed by build/degptr before any y write
    unsigned int* stg_r = (unsigned int*)y0;
    unsigned int* stg_c = (unsigned int*)y1;

    hipMemsetAsync(cnt_r, 0, (size_t)NBUCK * 4, stream);
    hipMemsetAsync(cnt_c, 0, (size_t)NBUCK * 4, stream);

    const int ablk = (E + CHUNK - 1) / CHUNK;  // 196
    bucket_count_kernel<<<ablk, 256, 0, stream>>>(row, col, cnt_r, cnt_c, E);
    bucket_scan_kernel<<<1, 256, 0, stream>>>(cnt_r, cnt_c, base_r, base_c, cur_r, cur_c);
    bucket_scatter_kernel<<<ablk, 256, 0, stream>>>(row, col, cur_r, stg_r, E);
    bucket_scatter_kernel<<<ablk, 256, 0, stream>>>(col, row, cur_c, stg_c, E);
    bucket_degptr_kernel<<<NBUCK, 512, 0, stream>>>(base_r, stg_r, row_ptr, dp_out, N);
    bucket_degptr_kernel<<<NBUCK, 512, 0, stream>>>(base_c, stg_c, col_ptr, dp_in, N);
    bucket_build_kernel<<<NBUCK, 256, 0, stream>>>(row_ptr, stg_r, csr_row_col, N);
    bucket_build_kernel<<<NBUCK, 256, 0, stream>>>(col_ptr, stg_c, csr_col_row, N);

    bias_total_kernel<<<1, 64, 0, stream>>>(b_sd, b_ds, bias_tot);
    prep_w_kernel<<<(6 * 4096 + 255) / 256, 256, 0, stream>>>(W_sd, W_ds, Wb);

    const int n8 = N * DF / 8;
    cvt_bf16_kernel<<<(n8 + 255) / 256, 256, 0, stream>>>(x, (uint*)x_bf, n8);

    const int spmm_blk = (N * 64 + 255) / 256;
    const int gblk = (N + 63) / 64;

    // chain: y0 = A x ; y1 = A y0 ; y2 = A y1   (bf16 payloads, fp32 accum)
    spmm_bf16_kernel<<<spmm_blk, 256, 0, stream>>>(row_ptr, csr_row_col, dp_out, dp_in,
                                                   x_bf, y0, N);
    spmm_bf16_kernel<<<spmm_blk, 256, 0, stream>>>(row_ptr, csr_row_col, dp_out, dp_in,
                                                   y0, y1, N);
    spmm_bf16_kernel<<<spmm_blk, 256, 0, stream>>>(row_ptr, csr_row_col, dp_out, dp_in,
                                                   y1, y2, N);

    // out = sum scale_i y_i Wsd_i^T ; zb = bf16(x Wds0^T + 0.5 y1 Wds1^T + 0.25 y2 Wds2^T)
    gemm_fused_kernel<<<gblk, 256, 0, stream>>>(y0, y1, y2, x_bf, Wb, out, zb, N);

    // out = 0.5*out + 0.5*(A^T zb) + bias_tot
    spmm_final_kernel<<<spmm_blk, 256, 0, stream>>>(col_ptr, csr_col_row, dp_in, dp_out,
                                                    zb, bias_tot, out, N);
}

// Round 8
// 316.658 us; speedup vs baseline: 4.6182x; 1.0884x over previous
//
#include <hip/hip_runtime.h>
#include <hip/hip_bf16.h>

#define N_NODES 100000
#define N_EDGES 1600000
#define DF 64

#define BSHIFT 9                       // 512 nodes per bucket
#define NBUCK ((N_NODES + 511) >> 9)   // 196
#define NBPAD 256
#define CHUNK 8192
#define CAP 10240                      // LDS slice capacity (mean 8192, +22 sigma)
#define CAPR 10240                     // fixed staging window per bucket

typedef unsigned int uint;
typedef unsigned short ushort;
typedef __attribute__((ext_vector_type(8))) short short8;
typedef __attribute__((ext_vector_type(4))) float f32x4;

__device__ __forceinline__ uint pack2_rne(float a, float b) {
    uint ua = __float_as_uint(a); ua = (ua + 0x7fffu + ((ua >> 16) & 1u)) >> 16;
    uint ub = __float_as_uint(b); ub = (ub + 0x7fffu + ((ub >> 16) & 1u)) >> 16;
    return ua | (ub << 16);
}
__device__ __forceinline__ ushort pack1_rne(float a) {
    uint u = __float_as_uint(a);
    return (ushort)((u + 0x7fffu + ((u >> 16) & 1u)) >> 16);
}

// ---------------- cursor init: staging cursors at fixed windows ----------------
__global__ void cursor_init_kernel(int* __restrict__ cur_r, int* __restrict__ cur_c) {
    int b = threadIdx.x;
    if (b < NBUCK) { cur_r[b] = b * CAPR; cur_c[b] = b * CAPR; }
}

// ---------------- scatter BOTH directions in one pass; coalesced staging writes ----------------
__global__ __launch_bounds__(256) void scatter_both_kernel(
        const int* __restrict__ row, const int* __restrict__ col,
        int* __restrict__ cur_r, int* __restrict__ cur_c,
        uint* __restrict__ stg_r, uint* __restrict__ stg_c, int E) {
    __shared__ uint stR[CHUNK];   // 32 KB
    __shared__ uint stC[CHUNK];   // 32 KB
    __shared__ int cR[NBPAD], sR[NBPAD], uR[NBPAD], gR[NBPAD];
    __shared__ int cC[NBPAD], sC[NBPAD], uC[NBPAD], gC[NBPAD];
    int t = threadIdx.x;
    int e0 = blockIdx.x * CHUNK;
    cR[t] = 0; cC[t] = 0; uR[t] = 0; uC[t] = 0;
    __syncthreads();
    for (int i = t; i < CHUNK; i += 256) {
        int e = e0 + i;
        if (e < E) {
            atomicAdd(&cR[row[e] >> BSHIFT], 1);
            atomicAdd(&cC[col[e] >> BSHIFT], 1);
        }
    }
    __syncthreads();
    int vR = cR[t], vC = cC[t];
    sR[t] = vR; sC[t] = vC;
    __syncthreads();
    for (int off = 1; off < 256; off <<= 1) {
        int aR = (t >= off) ? sR[t - off] : 0;
        int aC = (t >= off) ? sC[t - off] : 0;
        __syncthreads();
        sR[t] += aR; sC[t] += aC;
        __syncthreads();
    }
    int eR = sR[t] - vR, eC = sC[t] - vC;
    if (t < NBUCK) {
        if (vR > 0) gR[t] = atomicAdd(&cur_r[t], vR);
        if (vC > 0) gC[t] = atomicAdd(&cur_c[t], vC);
    }
    __syncthreads();
    sR[t] = eR; sC[t] = eC;
    __syncthreads();
    for (int i = t; i < CHUNK; i += 256) {
        int e = e0 + i;
        if (e < E) {
            int r = row[e], c = col[e];
            int br = r >> BSHIFT, bc = c >> BSHIFT;
            int pr = sR[br] + atomicAdd(&uR[br], 1);
            stR[pr] = ((uint)(r & 511) << 17) | (uint)c;
            int pc = sC[bc] + atomicAdd(&uC[bc], 1);
            stC[pc] = ((uint)(c & 511) << 17) | (uint)r;
        }
    }
    __syncthreads();
    int wave = t >> 6, lane = t & 63;
    for (int b = wave; b < NBUCK; b += 4) {
        int cnt = cR[b];
        if (cnt > 0) {
            int lb = sR[b], gb = gR[b];
            for (int j = lane; j < cnt; j += 64) stg_r[gb + j] = stR[lb + j];
        }
        cnt = cC[b];
        if (cnt > 0) {
            int lb = sC[b], gb = gC[b];
            for (int j = lane; j < cnt; j += 64) stg_c[gb + j] = stC[lb + j];
        }
    }
}

// ---------------- scan bucket counts -> CSR bases (both dirs, 1 block) ----------------
__global__ void count_scan_kernel(const int* __restrict__ cur_r, const int* __restrict__ cur_c,
                                  int* __restrict__ csrbase_r, int* __restrict__ csrbase_c) {
    __shared__ int s[256];
    int t = threadIdx.x;
    int v = (t < NBUCK) ? (cur_r[t] - t * CAPR) : 0;
    s[t] = v; __syncthreads();
    for (int off = 1; off < 256; off <<= 1) {
        int a = (t >= off) ? s[t - off] : 0; __syncthreads();
        s[t] += a; __syncthreads();
    }
    if (t < NBUCK) csrbase_r[t] = s[t] - v;
    if (t == NBUCK - 1) csrbase_r[NBUCK] = s[t];
    __syncthreads();
    int v2 = (t < NBUCK) ? (cur_c[t] - t * CAPR) : 0;
    s[t] = v2; __syncthreads();
    for (int off = 1; off < 256; off <<= 1) {
        int a = (t >= off) ? s[t - off] : 0; __syncthreads();
        s[t] += a; __syncthreads();
    }
    if (t < NBUCK) csrbase_c[t] = s[t] - v2;
    if (t == NBUCK - 1) csrbase_c[NBUCK] = s[t];
}

// ---------------- per bucket: degree hist -> ptr slice + dp + CSR build (one pass) ----------------
__global__ __launch_bounds__(512) void degptr_build_kernel(
        const int* __restrict__ cur, const int* __restrict__ csrbase,
        const uint* __restrict__ staging,
        int* __restrict__ ptr, float* __restrict__ dp, int* __restrict__ csr, int n) {
    __shared__ int cnt[512];
    __shared__ int sc[512];
    __shared__ int slice[CAP];
    int b = blockIdx.x, t = threadIdx.x;
    int lo = b << BSHIFT;
    int nn = min(n - lo, 512);
    int s0 = b * CAPR;
    int s1 = cur[b];
    int S = s1 - s0;
    int c0 = csrbase[b];
    cnt[t] = 0;
    __syncthreads();
    for (int i = s0 + t; i < s1; i += 512)
        atomicAdd(&cnt[staging[i] >> 17], 1);
    __syncthreads();
    int v = cnt[t];
    sc[t] = v;
    __syncthreads();
    for (int off = 1; off < 512; off <<= 1) {
        int a = (t >= off) ? sc[t - off] : 0;
        __syncthreads();
        sc[t] += a;
        __syncthreads();
    }
    int excl = sc[t] - v;
    if (t < nn) {
        ptr[lo + t] = c0 + excl;
        dp[lo + t] = (v > 0) ? rsqrtf(sqrtf((float)v)) : 0.f;
    }
    if (lo + t == n - 1) ptr[n] = c0 + sc[t];
    __syncthreads();
    sc[t] = excl;      // per-node exclusive offsets
    cnt[t] = 0;        // reuse as build cursor
    __syncthreads();
    if (S <= CAP) {
        for (int i = s0 + t; i < s1; i += 512) {
            uint w = staging[i];
            int rl = (int)(w >> 17), c = (int)(w & 0x1FFFFu);
            int pos = sc[rl] + atomicAdd(&cnt[rl], 1);
            slice[pos] = c;
        }
        __syncthreads();
        for (int i = t; i < S; i += 512) csr[c0 + i] = slice[i];
    } else {  // safety fallback
        for (int i = s0 + t; i < s1; i += 512) {
            uint w = staging[i];
            int rl = (int)(w >> 17), c = (int)(w & 0x1FFFFu);
            int pos = c0 + sc[rl] + atomicAdd(&cnt[rl], 1);
            csr[pos] = c;
        }
    }
}

// ---------------- x -> bf16 raw + bf16 pre-scaled (dp_in * x) ----------------
__global__ __launch_bounds__(256) void cvt_dual_kernel(
        const float* __restrict__ in, const float* __restrict__ dp,
        uint* __restrict__ raw, uint* __restrict__ scl, int n8) {
    int i = blockIdx.x * blockDim.x + threadIdx.x;   // 8 floats per thread
    if (i >= n8) return;
    float d = dp[i >> 3];
    const float4 a = ((const float4*)in)[i * 2];
    const float4 b = ((const float4*)in)[i * 2 + 1];
    uint4 o, s_;
    o.x = pack2_rne(a.x, a.y);         o.y = pack2_rne(a.z, a.w);
    o.z = pack2_rne(b.x, b.y);         o.w = pack2_rne(b.z, b.w);
    s_.x = pack2_rne(a.x * d, a.y * d); s_.y = pack2_rne(a.z * d, a.w * d);
    s_.z = pack2_rne(b.x * d, b.y * d); s_.w = pack2_rne(b.z * d, b.w * d);
    ((uint4*)raw)[i] = o;
    ((uint4*)scl)[i] = s_;
}

// ---------------- weight prep: 0.5*alpha folded; m 0..2 = Wsd, 3..5 = Wds ----------------
__global__ __launch_bounds__(256) void prep_w_kernel(const float* __restrict__ Wsd,
                                                     const float* __restrict__ Wds,
                                                     ushort* __restrict__ Wb) {
    int i = blockIdx.x * blockDim.x + threadIdx.x;
    if (i >= 6 * 4096) return;
    int m = i >> 12, r = i & 4095;
    int lv = (m >= 3) ? (m - 3) : m;
    float scale = 0.5f * ((lv == 0) ? 1.f : ((lv == 1) ? 0.5f : 0.25f));
    float v = ((m < 3) ? Wsd[lv * 4096 + r] : Wds[lv * 4096 + r]) * scale;
    Wb[i] = pack1_rne(v);
}

// ---------------- bias total ----------------
__global__ void bias_total_kernel(const float* __restrict__ b_sd, const float* __restrict__ b_ds,
                                  float* __restrict__ bias_tot) {
    int o = threadIdx.x;
    float s = 0.f, sc = 1.f;
    for (int i = 0; i < 3; ++i) {
        s += sc * (0.5f * b_sd[i * 64 + o] + 0.5f * b_ds[i * 64 + o]);
        sc *= 0.5f;
    }
    bias_tot[o] = s;
}

// ---------------- forward SpMM: gather pre-scaled rows; emit raw y and (optionally) pre-scaled y
__global__ __launch_bounds__(256) void spmm_fwd_kernel(
        const int* __restrict__ ptr, const int* __restrict__ nbr,
        const float* __restrict__ dp_dst, const float* __restrict__ dp_nxt,
        const ushort* __restrict__ srcs,
        ushort* __restrict__ y_raw, ushort* __restrict__ y_scl, int n, int wscl) {
    int wid = (blockIdx.x * blockDim.x + threadIdx.x) >> 6;
    int lane = threadIdx.x & 63;
    if (wid >= n) return;
    int slot = lane >> 3;
    int d8   = lane & 7;
    int beg = ptr[wid], end = ptr[wid + 1];
    float acc[8] = {};
    for (int p = beg + slot; p < end; p += 8) {
        int c = nbr[p];
        const uint4 u = *(const uint4*)&srcs[(size_t)c * DF + d8 * 8];
        acc[0] += __uint_as_float(u.x << 16);
        acc[1] += __uint_as_float(u.x & 0xffff0000u);
        acc[2] += __uint_as_float(u.y << 16);
        acc[3] += __uint_as_float(u.y & 0xffff0000u);
        acc[4] += __uint_as_float(u.z << 16);
        acc[5] += __uint_as_float(u.z & 0xffff0000u);
        acc[6] += __uint_as_float(u.w << 16);
        acc[7] += __uint_as_float(u.w & 0xffff0000u);
    }
#pragma unroll
    for (int m = 8; m <= 32; m <<= 1)
#pragma unroll
        for (int j = 0; j < 8; ++j) acc[j] += __shfl_xor(acc[j], m);
    if (slot == 0) {
        float s = dp_dst[wid];
        float r0 = acc[0] * s, r1 = acc[1] * s, r2 = acc[2] * s, r3 = acc[3] * s;
        float r4 = acc[4] * s, r5 = acc[5] * s, r6 = acc[6] * s, r7 = acc[7] * s;
        uint4 o;
        o.x = pack2_rne(r0, r1); o.y = pack2_rne(r2, r3);
        o.z = pack2_rne(r4, r5); o.w = pack2_rne(r6, r7);
        *(uint4*)&y_raw[(size_t)wid * DF + d8 * 8] = o;
        if (wscl) {
            float d = dp_nxt[wid];
            uint4 q;
            q.x = pack2_rne(r0 * d, r1 * d); q.y = pack2_rne(r2 * d, r3 * d);
            q.z = pack2_rne(r4 * d, r5 * d); q.w = pack2_rne(r6 * d, r7 * d);
            *(uint4*)&y_scl[(size_t)wid * DF + d8 * 8] = q;
        }
    }
}

// ---------------- final: out = oh + dp_in[r] * sum(zb') + bias ----------------
__global__ __launch_bounds__(256) void spmm_final_kernel(
        const int* __restrict__ ptr, const int* __restrict__ nbr,
        const float* __restrict__ dp_dst,
        const ushort* __restrict__ zb, const ushort* __restrict__ oh,
        const float* __restrict__ bias_tot, float* __restrict__ out, int n) {
    int wid = (blockIdx.x * blockDim.x + threadIdx.x) >> 6;
    int lane = threadIdx.x & 63;
    if (wid >= n) return;
    int slot = lane >> 3;
    int d8   = lane & 7;
    int beg = ptr[wid], end = ptr[wid + 1];
    float acc[8] = {};
    for (int p = beg + slot; p < end; p += 8) {
        int c = nbr[p];
        const uint4 u = *(const uint4*)&zb[(size_t)c * DF + d8 * 8];
        acc[0] += __uint_as_float(u.x << 16);
        acc[1] += __uint_as_float(u.x & 0xffff0000u);
        acc[2] += __uint_as_float(u.y << 16);
        acc[3] += __uint_as_float(u.y & 0xffff0000u);
        acc[4] += __uint_as_float(u.z << 16);
        acc[5] += __uint_as_float(u.z & 0xffff0000u);
        acc[6] += __uint_as_float(u.w << 16);
        acc[7] += __uint_as_float(u.w & 0xffff0000u);
    }
#pragma unroll
    for (int m = 8; m <= 32; m <<= 1)
#pragma unroll
        for (int j = 0; j < 8; ++j) acc[j] += __shfl_xor(acc[j], m);
    if (slot == 0) {
        float s = dp_dst[wid];
        const uint4 h = *(const uint4*)&oh[(size_t)wid * DF + d8 * 8];
        const float4 b0 = *(const float4*)&bias_tot[d8 * 8];
        const float4 b1 = *(const float4*)&bias_tot[d8 * 8 + 4];
        float4 p0, p1;
        p0.x = __uint_as_float(h.x << 16)         + s * acc[0] + b0.x;
        p0.y = __uint_as_float(h.x & 0xffff0000u) + s * acc[1] + b0.y;
        p0.z = __uint_as_float(h.y << 16)         + s * acc[2] + b0.z;
        p0.w = __uint_as_float(h.y & 0xffff0000u) + s * acc[3] + b0.w;
        p1.x = __uint_as_float(h.z << 16)         + s * acc[4] + b1.x;
        p1.y = __uint_as_float(h.z & 0xffff0000u) + s * acc[5] + b1.y;
        p1.z = __uint_as_float(h.w << 16)         + s * acc[6] + b1.z;
        p1.w = __uint_as_float(h.w & 0xffff0000u) + s * acc[7] + b1.w;
        float* op = &out[(size_t)wid * DF + d8 * 8];
        *(float4*)op = p0;
        *(float4*)(op + 4) = p1;
    }
}

// ---------------- fused MFMA GEMM:
//   oh  = bf16( y0*Wb0^T + y1*Wb1^T + y2*Wb2^T )              (0.5*scale in Wb)
//   zb' = bf16( dp_out[row] * (x*Wb3^T + y1*Wb4^T + y2*Wb5^T) )
__global__ __launch_bounds__(256) void gemm_fused_kernel(
        const ushort* __restrict__ y0, const ushort* __restrict__ y1,
        const ushort* __restrict__ y2, const ushort* __restrict__ xb,
        const ushort* __restrict__ Wb, const float* __restrict__ dp_out,
        ushort* __restrict__ oh, ushort* __restrict__ zb, int n) {
    __shared__ ushort wlds[6 * 4096];
    int t = threadIdx.x;
    for (int f = t; f < 3072; f += 256) {
        int c  = f & 15;
        int kq = (f >> 4) & 3;
        int ks = (f >> 6) & 1;
        int cb = (f >> 7) & 3;
        int m  = f >> 9;
        const uint4 v = *(const uint4*)&Wb[m * 4096 + (16 * cb + c) * 64 + ks * 32 + kq * 8];
        *(uint4*)&wlds[f * 8] = v;
    }
    __syncthreads();
    int w = t >> 6, lane = t & 63;
    int node0 = blockIdx.x * 64 + w * 16;
    int arow = node0 + (lane & 15);
    int kqo = (lane >> 4) * 8;
    f32x4 accO[4] = {};
    f32x4 accZ[4] = {};
#pragma unroll
    for (int ks = 0; ks < 2; ++ks) {
        int aoff = ks * 32 + kqo;
        short8 a0 = {}, a1 = {}, a2 = {}, ax = {};
        if (arow < n) {
            a0 = *(const short8*)&y0[(size_t)arow * DF + aoff];
            a1 = *(const short8*)&y1[(size_t)arow * DF + aoff];
            a2 = *(const short8*)&y2[(size_t)arow * DF + aoff];
            ax = *(const short8*)&xb[(size_t)arow * DF + aoff];
        }
#pragma unroll
        for (int cb = 0; cb < 4; ++cb) {
            const ushort* bp = &wlds[(((cb * 2 + ks) * 64) + lane) * 8];
            short8 b0 = *(const short8*)(bp);
            short8 b1 = *(const short8*)(bp + 4096);
            short8 b2 = *(const short8*)(bp + 8192);
            short8 b3 = *(const short8*)(bp + 12288);
            short8 b4 = *(const short8*)(bp + 16384);
            short8 b5 = *(const short8*)(bp + 20480);
            accO[cb] = __builtin_amdgcn_mfma_f32_16x16x32_bf16(a0, b0, accO[cb], 0, 0, 0);
            accO[cb] = __builtin_amdgcn_mfma_f32_16x16x32_bf16(a1, b1, accO[cb], 0, 0, 0);
            accO[cb] = __builtin_amdgcn_mfma_f32_16x16x32_bf16(a2, b2, accO[cb], 0, 0, 0);
            accZ[cb] = __builtin_amdgcn_mfma_f32_16x16x32_bf16(ax, b3, accZ[cb], 0, 0, 0);
            accZ[cb] = __builtin_amdgcn_mfma_f32_16x16x32_bf16(a1, b4, accZ[cb], 0, 0, 0);
            accZ[cb] = __builtin_amdgcn_mfma_f32_16x16x32_bf16(a2, b5, accZ[cb], 0, 0, 0);
        }
    }
#pragma unroll
    for (int r = 0; r < 4; ++r) {
        int nd = node0 + (lane >> 4) * 4 + r;
        if (nd < n) {
            float d = dp_out[nd];
#pragma unroll
            for (int cb = 0; cb < 4; ++cb) {
                int o = cb * 16 + (lane & 15);
                oh[(size_t)nd * DF + o] = pack1_rne(accO[cb][r]);
                zb[(size_t)nd * DF + o] = pack1_rne(accZ[cb][r] * d);
            }
        }
    }
}

extern "C" void kernel_launch(void* const* d_in, const int* in_sizes, int n_in,
                              void* d_out, int out_size, void* d_ws, size_t ws_size,
                              hipStream_t stream) {
    const int N = N_NODES, E = N_EDGES;
    const float* x    = (const float*)d_in[0];
    const int*   ei   = (const int*)d_in[1];
    const int*   row  = ei;
    const int*   col  = ei + E;
    const float* W_sd = (const float*)d_in[2];
    const float* b_sd = (const float*)d_in[3];
    const float* W_ds = (const float*)d_in[4];
    const float* b_ds = (const float*)d_in[5];
    float* out = (float*)d_out;

    char* ws = (char*)d_ws;
    size_t off = 0;
    auto alloc = [&](size_t bytes) -> void* {
        void* p = ws + off;
        off += (bytes + 255) & ~(size_t)255;
        return p;
    };
    int*   cur_r     = (int*)alloc((size_t)NBUCK * 4);
    int*   cur_c     = (int*)alloc((size_t)NBUCK * 4);
    int*   csrbase_r = (int*)alloc((size_t)(NBUCK + 1) * 4);
    int*   csrbase_c = (int*)alloc((size_t)(NBUCK + 1) * 4);
    int*   row_ptr   = (int*)alloc((size_t)(N + 1) * 4);
    int*   col_ptr   = (int*)alloc((size_t)(N + 1) * 4);
    float* dp_out    = (float*)alloc((size_t)N * 4);
    float* dp_in     = (float*)alloc((size_t)N * 4);
    int*   csr_row_col = (int*)alloc((size_t)E * 4);
    int*   csr_col_row = (int*)alloc((size_t)E * 4);
    float* bias_tot  = (float*)alloc(64 * 4);
    ushort* Wb   = (ushort*)alloc((size_t)6 * 4096 * 2);
    ushort* x_bf = (ushort*)alloc((size_t)N * DF * 2);
    ushort* x_s  = (ushort*)alloc((size_t)N * DF * 2);
    ushort* y0   = (ushort*)alloc((size_t)N * DF * 2);
    ushort* y1   = (ushort*)alloc((size_t)N * DF * 2);
    ushort* y2   = (ushort*)alloc((size_t)N * DF * 2);
    ushort* bufA = (ushort*)alloc((size_t)N * DF * 2);  // stg_r -> y0s -> zb
    ushort* bufB = (ushort*)alloc((size_t)N * DF * 2);  // stg_c -> y1s -> oh
    // timeline overlays (each 12.8 MB; staging needs NBUCK*CAPR*4 = 8.03 MB)
    uint*   stg_r = (uint*)bufA;
    uint*   stg_c = (uint*)bufB;
    ushort* y0s = bufA;
    ushort* y1s = bufB;
    ushort* zb  = bufA;
    ushort* oh  = bufB;

    cursor_init_kernel<<<1, 256, 0, stream>>>(cur_r, cur_c);
    const int ablk = (E + CHUNK - 1) / CHUNK;  // 196
    scatter_both_kernel<<<ablk, 256, 0, stream>>>(row, col, cur_r, cur_c, stg_r, stg_c, E);
    count_scan_kernel<<<1, 256, 0, stream>>>(cur_r, cur_c, csrbase_r, csrbase_c);
    degptr_build_kernel<<<NBUCK, 512, 0, stream>>>(cur_r, csrbase_r, stg_r,
                                                   row_ptr, dp_out, csr_row_col, N);
    degptr_build_kernel<<<NBUCK, 512, 0, stream>>>(cur_c, csrbase_c, stg_c,
                                                   col_ptr, dp_in, csr_col_row, N);

    bias_total_kernel<<<1, 64, 0, stream>>>(b_sd, b_ds, bias_tot);
    prep_w_kernel<<<(6 * 4096 + 255) / 256, 256, 0, stream>>>(W_sd, W_ds, Wb);

    const int n8 = N * DF / 8;
    cvt_dual_kernel<<<(n8 + 255) / 256, 256, 0, stream>>>(x, dp_in, (uint*)x_bf, (uint*)x_s, n8);

    const int spmm_blk = (N * 64 + 255) / 256;
    const int gblk = (N + 63) / 64;

    // forward chain (gathers read pre-scaled tables; no per-edge dp loads)
    spmm_fwd_kernel<<<spmm_blk, 256, 0, stream>>>(row_ptr, csr_row_col, dp_out, dp_in,
                                                  x_s, y0, y0s, N, 1);
    spmm_fwd_kernel<<<spmm_blk, 256, 0, stream>>>(row_ptr, csr_row_col, dp_out, dp_in,
                                                  y0s, y1, y1s, N, 1);
    spmm_fwd_kernel<<<spmm_blk, 256, 0, stream>>>(row_ptr, csr_row_col, dp_out, dp_in,
                                                  y1s, y2, (ushort*)0, N, 0);

    // oh = bf16(0.5*sum y_i Wsd_i^T) ; zb = bf16(dp_out * 0.5*(x Wds0 + 0.5 y1 Wds1 + 0.25 y2 Wds2))
    gemm_fused_kernel<<<gblk, 256, 0, stream>>>(y0, y1, y2, x_bf, Wb, dp_out, oh, zb, N);

    // out = oh + dp_in * (A^T-gather of zb) + bias
    spmm_final_kernel<<<spmm_blk, 256, 0, stream>>>(col_ptr, csr_col_row, dp_in,
                                                    zb, oh, bias_tot, out, N);
}

// Round 9
// 285.506 us; speedup vs baseline: 5.1220x; 1.1091x over previous
//
#include <hip/hip_runtime.h>
#include <hip/hip_bf16.h>

#define N_NODES 100000
#define N_EDGES 1600000
#define DF 64

#define BSHIFT 9                       // 512 nodes per bucket
#define NBUCK ((N_NODES + 511) >> 9)   // 196
#define NBPAD 256
#define CHUNK 4096                     // edges per scatter block (40KB LDS -> 4 blocks/CU)
#define CAP 10240                      // LDS slice capacity (mean 8192, +22 sigma)
#define CAPR 10240                     // fixed staging window per bucket

typedef unsigned int uint;
typedef unsigned short ushort;
typedef __attribute__((ext_vector_type(8))) short short8;
typedef __attribute__((ext_vector_type(4))) float f32x4;

__device__ __forceinline__ uint pack2_rne(float a, float b) {
    uint ua = __float_as_uint(a); ua = (ua + 0x7fffu + ((ua >> 16) & 1u)) >> 16;
    uint ub = __float_as_uint(b); ub = (ub + 0x7fffu + ((ub >> 16) & 1u)) >> 16;
    return ua | (ub << 16);
}
__device__ __forceinline__ ushort pack1_rne(float a) {
    uint u = __float_as_uint(a);
    return (ushort)((u + 0x7fffu + ((u >> 16) & 1u)) >> 16);
}

// ---------------- cursor init: staging cursors at fixed windows ----------------
__global__ void cursor_init_kernel(int* __restrict__ cur_r, int* __restrict__ cur_c) {
    int b = threadIdx.x;
    if (b < NBUCK) { cur_r[b] = b * CAPR; cur_c[b] = b * CAPR; }
}

// ---------------- scatter BOTH directions in one pass; coalesced staging writes ----------------
__global__ __launch_bounds__(256) void scatter_both_kernel(
        const int* __restrict__ row, const int* __restrict__ col,
        int* __restrict__ cur_r, int* __restrict__ cur_c,
        uint* __restrict__ stg_r, uint* __restrict__ stg_c, int E) {
    __shared__ uint stR[CHUNK];   // 16 KB
    __shared__ uint stC[CHUNK];   // 16 KB
    __shared__ int cR[NBPAD], sR[NBPAD], uR[NBPAD], gR[NBPAD];
    __shared__ int cC[NBPAD], sC[NBPAD], uC[NBPAD], gC[NBPAD];
    int t = threadIdx.x;
    int e0 = blockIdx.x * CHUNK;
    cR[t] = 0; cC[t] = 0; uR[t] = 0; uC[t] = 0;
    __syncthreads();
    for (int i = t; i < CHUNK; i += 256) {
        int e = e0 + i;
        if (e < E) {
            atomicAdd(&cR[row[e] >> BSHIFT], 1);
            atomicAdd(&cC[col[e] >> BSHIFT], 1);
        }
    }
    __syncthreads();
    int vR = cR[t], vC = cC[t];
    sR[t] = vR; sC[t] = vC;
    __syncthreads();
    for (int off = 1; off < 256; off <<= 1) {
        int aR = (t >= off) ? sR[t - off] : 0;
        int aC = (t >= off) ? sC[t - off] : 0;
        __syncthreads();
        sR[t] += aR; sC[t] += aC;
        __syncthreads();
    }
    int eR = sR[t] - vR, eC = sC[t] - vC;
    if (t < NBUCK) {
        if (vR > 0) gR[t] = atomicAdd(&cur_r[t], vR);
        if (vC > 0) gC[t] = atomicAdd(&cur_c[t], vC);
    }
    __syncthreads();
    sR[t] = eR; sC[t] = eC;
    __syncthreads();
    for (int i = t; i < CHUNK; i += 256) {
        int e = e0 + i;
        if (e < E) {
            int r = row[e], c = col[e];
            int br = r >> BSHIFT, bc = c >> BSHIFT;
            int pr = sR[br] + atomicAdd(&uR[br], 1);
            stR[pr] = ((uint)(r & 511) << 17) | (uint)c;
            int pc = sC[bc] + atomicAdd(&uC[bc], 1);
            stC[pc] = ((uint)(c & 511) << 17) | (uint)r;
        }
    }
    __syncthreads();
    int wave = t >> 6, lane = t & 63;
    for (int b = wave; b < NBUCK; b += 4) {
        int cnt = cR[b];
        if (cnt > 0) {
            int lb = sR[b], gb = gR[b];
            for (int j = lane; j < cnt; j += 64) stg_r[gb + j] = stR[lb + j];
        }
        cnt = cC[b];
        if (cnt > 0) {
            int lb = sC[b], gb = gC[b];
            for (int j = lane; j < cnt; j += 64) stg_c[gb + j] = stC[lb + j];
        }
    }
}

// ---------------- scan bucket counts -> CSR bases (both dirs, 1 block) ----------------
__global__ void count_scan_kernel(const int* __restrict__ cur_r, const int* __restrict__ cur_c,
                                  int* __restrict__ csrbase_r, int* __restrict__ csrbase_c) {
    __shared__ int s[256];
    int t = threadIdx.x;
    int v = (t < NBUCK) ? (cur_r[t] - t * CAPR) : 0;
    s[t] = v; __syncthreads();
    for (int off = 1; off < 256; off <<= 1) {
        int a = (t >= off) ? s[t - off] : 0; __syncthreads();
        s[t] += a; __syncthreads();
    }
    if (t < NBUCK) csrbase_r[t] = s[t] - v;
    if (t == NBUCK - 1) csrbase_r[NBUCK] = s[t];
    __syncthreads();
    int v2 = (t < NBUCK) ? (cur_c[t] - t * CAPR) : 0;
    s[t] = v2; __syncthreads();
    for (int off = 1; off < 256; off <<= 1) {
        int a = (t >= off) ? s[t - off] : 0; __syncthreads();
        s[t] += a; __syncthreads();
    }
    if (t < NBUCK) csrbase_c[t] = s[t] - v2;
    if (t == NBUCK - 1) csrbase_c[NBUCK] = s[t];
}

// ---------------- per bucket (both dirs in one grid): degree hist -> ptr + dp + CSR ----------------
__global__ __launch_bounds__(512) void degptr_build2_kernel(
        const int* __restrict__ cur_r, const int* __restrict__ cur_c,
        const int* __restrict__ csrbase_r, const int* __restrict__ csrbase_c,
        const uint* __restrict__ stg_r, const uint* __restrict__ stg_c,
        int* __restrict__ row_ptr, int* __restrict__ col_ptr,
        float* __restrict__ dp_out, float* __restrict__ dp_in,
        int* __restrict__ csr_r, int* __restrict__ csr_c, int n) {
    __shared__ int cnt[512];
    __shared__ int sc[512];
    __shared__ int slice[CAP];
    int blk = blockIdx.x, t = threadIdx.x;
    int dir = (blk >= NBUCK);
    int b = dir ? (blk - NBUCK) : blk;
    const int*  cur     = dir ? cur_c : cur_r;
    const int*  csrbase = dir ? csrbase_c : csrbase_r;
    const uint* staging = dir ? stg_c : stg_r;
    int* ptr = dir ? col_ptr : row_ptr;
    float* dp = dir ? dp_in : dp_out;
    int* csr = dir ? csr_c : csr_r;

    int lo = b << BSHIFT;
    int nn = min(n - lo, 512);
    int s0 = b * CAPR;
    int s1 = cur[b];
    int S = s1 - s0;
    int c0 = csrbase[b];
    cnt[t] = 0;
    __syncthreads();
    for (int i = s0 + t; i < s1; i += 512)
        atomicAdd(&cnt[staging[i] >> 17], 1);
    __syncthreads();
    int v = cnt[t];
    sc[t] = v;
    __syncthreads();
    for (int off = 1; off < 512; off <<= 1) {
        int a = (t >= off) ? sc[t - off] : 0;
        __syncthreads();
        sc[t] += a;
        __syncthreads();
    }
    int excl = sc[t] - v;
    if (t < nn) {
        ptr[lo + t] = c0 + excl;
        dp[lo + t] = (v > 0) ? rsqrtf(sqrtf((float)v)) : 0.f;
    }
    if (lo + t == n - 1) ptr[n] = c0 + sc[t];
    __syncthreads();
    sc[t] = excl;      // per-node exclusive offsets
    cnt[t] = 0;        // reuse as build cursor
    __syncthreads();
    if (S <= CAP) {
        for (int i = s0 + t; i < s1; i += 512) {
            uint w = staging[i];
            int rl = (int)(w >> 17), c = (int)(w & 0x1FFFFu);
            int pos = sc[rl] + atomicAdd(&cnt[rl], 1);
            slice[pos] = c;
        }
        __syncthreads();
        for (int i = t; i < S; i += 512) csr[c0 + i] = slice[i];
    } else {  // safety fallback
        for (int i = s0 + t; i < s1; i += 512) {
            uint w = staging[i];
            int rl = (int)(w >> 17), c = (int)(w & 0x1FFFFu);
            int pos = c0 + sc[rl] + atomicAdd(&cnt[rl], 1);
            csr[pos] = c;
        }
    }
}

// ---------------- x -> bf16 raw + bf16 pre-scaled (dp_in * x) ----------------
__global__ __launch_bounds__(256) void cvt_dual_kernel(
        const float* __restrict__ in, const float* __restrict__ dp,
        uint* __restrict__ raw, uint* __restrict__ scl, int n8) {
    int i = blockIdx.x * blockDim.x + threadIdx.x;   // 8 floats per thread
    if (i >= n8) return;
    float d = dp[i >> 3];
    const float4 a = ((const float4*)in)[i * 2];
    const float4 b = ((const float4*)in)[i * 2 + 1];
    uint4 o, s_;
    o.x = pack2_rne(a.x, a.y);         o.y = pack2_rne(a.z, a.w);
    o.z = pack2_rne(b.x, b.y);         o.w = pack2_rne(b.z, b.w);
    s_.x = pack2_rne(a.x * d, a.y * d); s_.y = pack2_rne(a.z * d, a.w * d);
    s_.z = pack2_rne(b.x * d, b.y * d); s_.w = pack2_rne(b.z * d, b.w * d);
    ((uint4*)raw)[i] = o;
    ((uint4*)scl)[i] = s_;
}

// ---------------- weight prep: 0.5*alpha folded; m 0..2 = Wsd, 3..5 = Wds ----------------
__global__ __launch_bounds__(256) void prep_w_kernel(const float* __restrict__ Wsd,
                                                     const float* __restrict__ Wds,
                                                     ushort* __restrict__ Wb) {
    int i = blockIdx.x * blockDim.x + threadIdx.x;
    if (i >= 6 * 4096) return;
    int m = i >> 12, r = i & 4095;
    int lv = (m >= 3) ? (m - 3) : m;
    float scale = 0.5f * ((lv == 0) ? 1.f : ((lv == 1) ? 0.5f : 0.25f));
    float v = ((m < 3) ? Wsd[lv * 4096 + r] : Wds[lv * 4096 + r]) * scale;
    Wb[i] = pack1_rne(v);
}

// ---------------- bias total ----------------
__global__ void bias_total_kernel(const float* __restrict__ b_sd, const float* __restrict__ b_ds,
                                  float* __restrict__ bias_tot) {
    int o = threadIdx.x;
    float s = 0.f, sc = 1.f;
    for (int i = 0; i < 3; ++i) {
        s += sc * (0.5f * b_sd[i * 64 + o] + 0.5f * b_ds[i * 64 + o]);
        sc *= 0.5f;
    }
    bias_tot[o] = s;
}

#define ACC8(u)                                        \
    acc[0] += __uint_as_float((u).x << 16);            \
    acc[1] += __uint_as_float((u).x & 0xffff0000u);    \
    acc[2] += __uint_as_float((u).y << 16);            \
    acc[3] += __uint_as_float((u).y & 0xffff0000u);    \
    acc[4] += __uint_as_float((u).z << 16);            \
    acc[5] += __uint_as_float((u).z & 0xffff0000u);    \
    acc[6] += __uint_as_float((u).w << 16);            \
    acc[7] += __uint_as_float((u).w & 0xffff0000u);

// ---------------- forward SpMM: gather pre-scaled rows; emit raw y and (optionally) pre-scaled y
__global__ __launch_bounds__(256) void spmm_fwd_kernel(
        const int* __restrict__ ptr, const int* __restrict__ nbr,
        const float* __restrict__ dp_dst, const float* __restrict__ dp_nxt,
        const ushort* __restrict__ srcs,
        ushort* __restrict__ y_raw, ushort* __restrict__ y_scl, int n, int wscl) {
    int wid = (blockIdx.x * blockDim.x + threadIdx.x) >> 6;
    int lane = threadIdx.x & 63;
    if (wid >= n) return;
    int slot = lane >> 3;
    int d8   = lane & 7;
    int beg = ptr[wid], end = ptr[wid + 1];
    float acc[8] = {};
    int p = beg + slot;
    for (; p + 8 < end; p += 16) {   // unroll x2: two independent gathers in flight
        int c0 = nbr[p], c1 = nbr[p + 8];
        const uint4 u0 = *(const uint4*)&srcs[(size_t)c0 * DF + d8 * 8];
        const uint4 u1 = *(const uint4*)&srcs[(size_t)c1 * DF + d8 * 8];
        ACC8(u0);
        ACC8(u1);
    }
    if (p < end) {
        int c0 = nbr[p];
        const uint4 u0 = *(const uint4*)&srcs[(size_t)c0 * DF + d8 * 8];
        ACC8(u0);
    }
#pragma unroll
    for (int m = 8; m <= 32; m <<= 1)
#pragma unroll
        for (int j = 0; j < 8; ++j) acc[j] += __shfl_xor(acc[j], m);
    if (slot == 0) {
        float s = dp_dst[wid];
        float r0 = acc[0] * s, r1 = acc[1] * s, r2 = acc[2] * s, r3 = acc[3] * s;
        float r4 = acc[4] * s, r5 = acc[5] * s, r6 = acc[6] * s, r7 = acc[7] * s;
        uint4 o;
        o.x = pack2_rne(r0, r1); o.y = pack2_rne(r2, r3);
        o.z = pack2_rne(r4, r5); o.w = pack2_rne(r6, r7);
        *(uint4*)&y_raw[(size_t)wid * DF + d8 * 8] = o;
        if (wscl) {
            float d = dp_nxt[wid];
            uint4 q;
            q.x = pack2_rne(r0 * d, r1 * d); q.y = pack2_rne(r2 * d, r3 * d);
            q.z = pack2_rne(r4 * d, r5 * d); q.w = pack2_rne(r6 * d, r7 * d);
            *(uint4*)&y_scl[(size_t)wid * DF + d8 * 8] = q;
        }
    }
}

// ---------------- final: out = oh + dp_in[r] * sum(zb') + bias ----------------
__global__ __launch_bounds__(256) void spmm_final_kernel(
        const int* __restrict__ ptr, const int* __restrict__ nbr,
        const float* __restrict__ dp_dst,
        const ushort* __restrict__ zb, const ushort* __restrict__ oh,
        const float* __restrict__ bias_tot, float* __restrict__ out, int n) {
    int wid = (blockIdx.x * blockDim.x + threadIdx.x) >> 6;
    int lane = threadIdx.x & 63;
    if (wid >= n) return;
    int slot = lane >> 3;
    int d8   = lane & 7;
    int beg = ptr[wid], end = ptr[wid + 1];
    float acc[8] = {};
    int p = beg + slot;
    for (; p + 8 < end; p += 16) {
        int c0 = nbr[p], c1 = nbr[p + 8];
        const uint4 u0 = *(const uint4*)&zb[(size_t)c0 * DF + d8 * 8];
        const uint4 u1 = *(const uint4*)&zb[(size_t)c1 * DF + d8 * 8];
        ACC8(u0);
        ACC8(u1);
    }
    if (p < end) {
        int c0 = nbr[p];
        const uint4 u0 = *(const uint4*)&zb[(size_t)c0 * DF + d8 * 8];
        ACC8(u0);
    }
#pragma unroll
    for (int m = 8; m <= 32; m <<= 1)
#pragma unroll
        for (int j = 0; j < 8; ++j) acc[j] += __shfl_xor(acc[j], m);
    if (slot == 0) {
        float s = dp_dst[wid];
        const uint4 h = *(const uint4*)&oh[(size_t)wid * DF + d8 * 8];
        const float4 b0 = *(const float4*)&bias_tot[d8 * 8];
        const float4 b1 = *(const float4*)&bias_tot[d8 * 8 + 4];
        float4 p0, p1;
        p0.x = __uint_as_float(h.x << 16)         + s * acc[0] + b0.x;
        p0.y = __uint_as_float(h.x & 0xffff0000u) + s * acc[1] + b0.y;
        p0.z = __uint_as_float(h.y << 16)         + s * acc[2] + b0.z;
        p0.w = __uint_as_float(h.y & 0xffff0000u) + s * acc[3] + b0.w;
        p1.x = __uint_as_float(h.z << 16)         + s * acc[4] + b1.x;
        p1.y = __uint_as_float(h.z & 0xffff0000u) + s * acc[5] + b1.y;
        p1.z = __uint_as_float(h.w << 16)         + s * acc[6] + b1.z;
        p1.w = __uint_as_float(h.w & 0xffff0000u) + s * acc[7] + b1.w;
        float* op = &out[(size_t)wid * DF + d8 * 8];
        *(float4*)op = p0;
        *(float4*)(op + 4) = p1;
    }
}

// ---------------- fused MFMA GEMM:
//   oh  = bf16( y0*Wb0^T + y1*Wb1^T + y2*Wb2^T )              (0.5*scale in Wb)
//   zb' = bf16( dp_out[row] * (x*Wb3^T + y1*Wb4^T + y2*Wb5^T) )
__global__ __launch_bounds__(256) void gemm_fused_kernel(
        const ushort* __restrict__ y0, const ushort* __restrict__ y1,
        const ushort* __restrict__ y2, const ushort* __restrict__ xb,
        const ushort* __restrict__ Wb, const float* __restrict__ dp_out,
        ushort* __restrict__ oh, ushort* __restrict__ zb, int n) {
    __shared__ ushort wlds[6 * 4096];
    int t = threadIdx.x;
    for (int f = t; f < 3072; f += 256) {
        int c  = f & 15;
        int kq = (f >> 4) & 3;
        int ks = (f >> 6) & 1;
        int cb = (f >> 7) & 3;
        int m  = f >> 9;
        const uint4 v = *(const uint4*)&Wb[m * 4096 + (16 * cb + c) * 64 + ks * 32 + kq * 8];
        *(uint4*)&wlds[f * 8] = v;
    }
    __syncthreads();
    int w = t >> 6, lane = t & 63;
    int node0 = blockIdx.x * 64 + w * 16;
    int arow = node0 + (lane & 15);
    int kqo = (lane >> 4) * 8;
    f32x4 accO[4] = {};
    f32x4 accZ[4] = {};
#pragma unroll
    for (int ks = 0; ks < 2; ++ks) {
        int aoff = ks * 32 + kqo;
        short8 a0 = {}, a1 = {}, a2 = {}, ax = {};
        if (arow < n) {
            a0 = *(const short8*)&y0[(size_t)arow * DF + aoff];
            a1 = *(const short8*)&y1[(size_t)arow * DF + aoff];
            a2 = *(const short8*)&y2[(size_t)arow * DF + aoff];
            ax = *(const short8*)&xb[(size_t)arow * DF + aoff];
        }
#pragma unroll
        for (int cb = 0; cb < 4; ++cb) {
            const ushort* bp = &wlds[(((cb * 2 + ks) * 64) + lane) * 8];
            short8 b0 = *(const short8*)(bp);
            short8 b1 = *(const short8*)(bp + 4096);
            short8 b2 = *(const short8*)(bp + 8192);
            short8 b3 = *(const short8*)(bp + 12288);
            short8 b4 = *(const short8*)(bp + 16384);
            short8 b5 = *(const short8*)(bp + 20480);
            accO[cb] = __builtin_amdgcn_mfma_f32_16x16x32_bf16(a0, b0, accO[cb], 0, 0, 0);
            accO[cb] = __builtin_amdgcn_mfma_f32_16x16x32_bf16(a1, b1, accO[cb], 0, 0, 0);
            accO[cb] = __builtin_amdgcn_mfma_f32_16x16x32_bf16(a2, b2, accO[cb], 0, 0, 0);
            accZ[cb] = __builtin_amdgcn_mfma_f32_16x16x32_bf16(ax, b3, accZ[cb], 0, 0, 0);
            accZ[cb] = __builtin_amdgcn_mfma_f32_16x16x32_bf16(a1, b4, accZ[cb], 0, 0, 0);
            accZ[cb] = __builtin_amdgcn_mfma_f32_16x16x32_bf16(a2, b5, accZ[cb], 0, 0, 0);
        }
    }
#pragma unroll
    for (int r = 0; r < 4; ++r) {
        int nd = node0 + (lane >> 4) * 4 + r;
        if (nd < n) {
            float d = dp_out[nd];
#pragma unroll
            for (int cb = 0; cb < 4; ++cb) {
                int o = cb * 16 + (lane & 15);
                oh[(size_t)nd * DF + o] = pack1_rne(accO[cb][r]);
                zb[(size_t)nd * DF + o] = pack1_rne(accZ[cb][r] * d);
            }
        }
    }
}

extern "C" void kernel_launch(void* const* d_in, const int* in_sizes, int n_in,
                              void* d_out, int out_size, void* d_ws, size_t ws_size,
                              hipStream_t stream) {
    const int N = N_NODES, E = N_EDGES;
    const float* x    = (const float*)d_in[0];
    const int*   ei   = (const int*)d_in[1];
    const int*   row  = ei;
    const int*   col  = ei + E;
    const float* W_sd = (const float*)d_in[2];
    const float* b_sd = (const float*)d_in[3];
    const float* W_ds = (const float*)d_in[4];
    const float* b_ds = (const float*)d_in[5];
    float* out = (float*)d_out;

    char* ws = (char*)d_ws;
    size_t off = 0;
    auto alloc = [&](size_t bytes) -> void* {
        void* p = ws + off;
        off += (bytes + 255) & ~(size_t)255;
        return p;
    };
    int*   cur_r     = (int*)alloc((size_t)NBUCK * 4);
    int*   cur_c     = (int*)alloc((size_t)NBUCK * 4);
    int*   csrbase_r = (int*)alloc((size_t)(NBUCK + 1) * 4);
    int*   csrbase_c = (int*)alloc((size_t)(NBUCK + 1) * 4);
    int*   row_ptr   = (int*)alloc((size_t)(N + 1) * 4);
    int*   col_ptr   = (int*)alloc((size_t)(N + 1) * 4);
    float* dp_out    = (float*)alloc((size_t)N * 4);
    float* dp_in     = (float*)alloc((size_t)N * 4);
    int*   csr_row_col = (int*)alloc((size_t)E * 4);
    int*   csr_col_row = (int*)alloc((size_t)E * 4);
    float* bias_tot  = (float*)alloc(64 * 4);
    ushort* Wb   = (ushort*)alloc((size_t)6 * 4096 * 2);
    ushort* x_bf = (ushort*)alloc((size_t)N * DF * 2);
    ushort* x_s  = (ushort*)alloc((size_t)N * DF * 2);
    ushort* y0   = (ushort*)alloc((size_t)N * DF * 2);
    ushort* y1   = (ushort*)alloc((size_t)N * DF * 2);
    ushort* y2   = (ushort*)alloc((size_t)N * DF * 2);
    ushort* bufA = (ushort*)alloc((size_t)N * DF * 2);  // stg_r -> y0s -> zb
    ushort* bufB = (ushort*)alloc((size_t)N * DF * 2);  // stg_c -> y1s -> oh
    // timeline overlays (each 12.8 MB; staging needs NBUCK*CAPR*4 = 8.03 MB)
    uint*   stg_r = (uint*)bufA;
    uint*   stg_c = (uint*)bufB;
    ushort* y0s = bufA;
    ushort* y1s = bufB;
    ushort* zb  = bufA;
    ushort* oh  = bufB;

    cursor_init_kernel<<<1, 256, 0, stream>>>(cur_r, cur_c);
    const int ablk = (E + CHUNK - 1) / CHUNK;  // 391
    scatter_both_kernel<<<ablk, 256, 0, stream>>>(row, col, cur_r, cur_c, stg_r, stg_c, E);
    count_scan_kernel<<<1, 256, 0, stream>>>(cur_r, cur_c, csrbase_r, csrbase_c);
    degptr_build2_kernel<<<2 * NBUCK, 512, 0, stream>>>(
        cur_r, cur_c, csrbase_r, csrbase_c, stg_r, stg_c,
        row_ptr, col_ptr, dp_out, dp_in, csr_row_col, csr_col_row, N);

    bias_total_kernel<<<1, 64, 0, stream>>>(b_sd, b_ds, bias_tot);
    prep_w_kernel<<<(6 * 4096 + 255) / 256, 256, 0, stream>>>(W_sd, W_ds, Wb);

    const int n8 = N * DF / 8;
    cvt_dual_kernel<<<(n8 + 255) / 256, 256, 0, stream>>>(x, dp_in, (uint*)x_bf, (uint*)x_s, n8);

    const int spmm_blk = (N * 64 + 255) / 256;
    const int gblk = (N + 63) / 64;

    // forward chain (gathers read pre-scaled tables; no per-edge dp loads)
    spmm_fwd_kernel<<<spmm_blk, 256, 0, stream>>>(row_ptr, csr_row_col, dp_out, dp_in,
                                                  x_s, y0, y0s, N, 1);
    spmm_fwd_kernel<<<spmm_blk, 256, 0, stream>>>(row_ptr, csr_row_col, dp_out, dp_in,
                                                  y0s, y1, y1s, N, 1);
    spmm_fwd_kernel<<<spmm_blk, 256, 0, stream>>>(row_ptr, csr_row_col, dp_out, dp_in,
                                                  y1s, y2, (ushort*)0, N, 0);

    // oh = bf16(0.5*sum y_i Wsd_i^T) ; zb = bf16(dp_out * 0.5*(x Wds0 + 0.5 y1 Wds1 + 0.25 y2 Wds2))
    gemm_fused_kernel<<<gblk, 256, 0, stream>>>(y0, y1, y2, x_bf, Wb, dp_out, oh, zb, N);

    // out = oh + dp_in * (A^T-gather of zb) + bias
    spmm_final_kernel<<<spmm_blk, 256, 0, stream>>>(col_ptr, csr_col_row, dp_in,
                                                    zb, oh, bias_tot, out, N);
}